// Round 7
// baseline (2117.918 us; speedup 1.0000x reference)
//
#include <hip/hip_runtime.h>
#include <math.h>

#define NPOOL 4096
#define NSEQ  512
#define NF    20
#define EDIM  64
#define GDIM  128
#define SDIM  16
#define ALPH  20
#define SPLITK 16
#define KSLICE (NPOOL / SPLITK)   // 256

__device__ __forceinline__ double relu_d(double x){ return x > 0.0 ? x : 0.0; }
__device__ __forceinline__ double sigm_d(double x){ return 1.0 / (1.0 + exp(-x)); }

__device__ __forceinline__ unsigned long long sortable_u64(double x) {
    x = x + 0.0;                                  // canonicalize -0 -> +0
    unsigned long long b = (unsigned long long)__double_as_longlong(x);
    return b ^ ((b >> 63) ? ~0ULL : 0x8000000000000000ULL);
}

// Fin[i][e] = f @ w_feat + b_feat (f64); R = relu(Fin). Also zeroes T1,T2,T3.
__global__ __launch_bounds__(256) void k_prep(const float* __restrict__ f, const float* __restrict__ wf,
                       const float* __restrict__ bf, double* __restrict__ Fin, double* __restrict__ R,
                       double* __restrict__ T1z, double* __restrict__ T2z, double* __restrict__ T3z) {
    int t = blockIdx.x * 256 + threadIdx.x;   // NPOOL*EDIM
    int i = t >> 6, e = t & 63;
    double acc = (double)bf[e];
#pragma unroll
    for (int j = 0; j < NF; ++j)
        acc += (double)f[i * NF + j] * (double)wf[j * EDIM + e];
    Fin[t] = acc;
    R[t] = acc > 0.0 ? acc : 0.0;
    T1z[t] = 0.0; T2z[t] = 0.0; T3z[t] = 0.0;
}

// seq_embed = x @ w_seq + b_seq (f64). Also inits rank[].
__global__ __launch_bounds__(256) void k_seqe(const float* __restrict__ x, const float* __restrict__ wsq,
                       const float* __restrict__ bsq, double* __restrict__ seqe, int* __restrict__ rank) {
    int t = blockIdx.x * 256 + threadIdx.x;   // NSEQ*SDIM = 8192
    int k = t >> 4, s = t & 15;
    double acc = (double)bsq[s];
#pragma unroll
    for (int q = 0; q < ALPH; ++q)
        acc += (double)x[k * ALPH + q] * (double)wsq[q * SDIM + s];
    seqe[t] = acc;
    if (t < NPOOL) rank[t] = 1 << 30;
}

// C(4096x64 f64) += A(4096x4096 f32) @ B(4096x64 f64), split-K, VALU f64 FMA.
// LDS-instruction-rate optimized: 128x64 block, 256 threads (16tx x 16ty),
// thread = 8 rows (8ty..8ty+7) x 4 cols {2tx,2tx+1,2tx+32,2tx+33}.
// A kept as f32 in LDS (exact: A input is f32): per kk only 2 f32-b128 (A) + 2 f64-b128 (B)
// reads per 32 MACs (v3 was 4 reads per 16 MACs -> 3x fewer LDS instrs/MAC).
// A-read = quarter-wave broadcast (free); B-read 2-way (free).
// A-write swizzle slot = r ^ ((k>>3)<<2): 16 distinct banks per quarter-wave (conflict-free);
// read un-swizzles via compile-time lo/hi float4 swap (kk unrolled).
// Register-staged double-buffer hides global latency across the barrier.
__global__ __launch_bounds__(256, 2) void gemm_f64_v7(const float* __restrict__ A, const double* __restrict__ B,
                                                      double* __restrict__ C) {
    __shared__ float  As[32][132];   // [k][row-slot swizzled], f32
    __shared__ double Bs[32][66];    // [k][col]
    int t  = threadIdx.x;
    int tx = t & 15;
    int ty = t >> 4;
    int row0 = blockIdx.x * 128;
    int k0   = blockIdx.y * KSLICE;
    int kq = t & 3, kb = kq << 3;    // staging: this thread covers k = kb..kb+7
    int ar = t >> 2;                 // staging A row (0..63; +64 for second half)

    double acc[8][4] = {};
    float4  pa[2][2];                // staged A: [half][lo/hi float4]
    double2 pb[4];                   // staged B: 8 doubles

#define LOADG(KT)                                                                  \
    {                                                                              \
        _Pragma("unroll")                                                          \
        for (int h = 0; h < 2; ++h) {                                              \
            const float* Ap = A + (size_t)(row0 + ar + 64 * h) * NPOOL + (KT) + kq * 8; \
            pa[h][0] = *(const float4*)Ap;                                         \
            pa[h][1] = *(const float4*)(Ap + 4);                                   \
        }                                                                          \
        _Pragma("unroll")                                                          \
        for (int it = 0; it < 4; ++it) {                                           \
            int e = 2 * t + 512 * it;                                              \
            pb[it] = *(const double2*)&B[(size_t)((KT) + (e >> 6)) * 64 + (e & 63)]; \
        }                                                                          \
    }

#define STORELDS()                                                                 \
    {                                                                              \
        _Pragma("unroll")                                                          \
        for (int h = 0; h < 2; ++h) {                                              \
            int rs = (ar + 64 * h) ^ (kq << 2);                                    \
            As[kb + 0][rs] = pa[h][0].x; As[kb + 1][rs] = pa[h][0].y;              \
            As[kb + 2][rs] = pa[h][0].z; As[kb + 3][rs] = pa[h][0].w;              \
            As[kb + 4][rs] = pa[h][1].x; As[kb + 5][rs] = pa[h][1].y;              \
            As[kb + 6][rs] = pa[h][1].z; As[kb + 7][rs] = pa[h][1].w;              \
        }                                                                          \
        _Pragma("unroll")                                                          \
        for (int it = 0; it < 4; ++it) {                                           \
            int e = 2 * t + 512 * it;                                              \
            *(double2*)&Bs[e >> 6][e & 63] = pb[it];                               \
        }                                                                          \
    }

    LOADG(k0)
    STORELDS()
    __syncthreads();

    for (int kt = k0; kt < k0 + KSLICE; kt += 32) {
        bool more = (kt + 32 < k0 + KSLICE);
        if (more) LOADG(kt + 32)
#pragma unroll
        for (int kk = 0; kk < 32; ++kk) {
            const int kqr = kk >> 3;
            int abase = 8 * (ty ^ (kqr >> 1));
            float4 alo = *(const float4*)&As[kk][abase];
            float4 ahi = *(const float4*)&As[kk][abase + 4];
            if (kqr & 1) { float4 tmp = alo; alo = ahi; ahi = tmp; }  // compile-time
            double a[8] = {(double)alo.x, (double)alo.y, (double)alo.z, (double)alo.w,
                           (double)ahi.x, (double)ahi.y, (double)ahi.z, (double)ahi.w};
            double2 b01 = *(const double2*)&Bs[kk][2 * tx];
            double2 b23 = *(const double2*)&Bs[kk][2 * tx + 32];
            double b[4] = {b01.x, b01.y, b23.x, b23.y};
#pragma unroll
            for (int i = 0; i < 8; ++i)
#pragma unroll
                for (int j = 0; j < 4; ++j)
                    acc[i][j] = fma(a[i], b[j], acc[i][j]);
        }
        __syncthreads();
        if (more) STORELDS()
        __syncthreads();
    }
#undef LOADG
#undef STORELDS

    int cc[4] = {2 * tx, 2 * tx + 1, 2 * tx + 32, 2 * tx + 33};
#pragma unroll
    for (int i = 0; i < 8; ++i)
#pragma unroll
        for (int j = 0; j < 4; ++j)
            unsafeAtomicAdd(&C[(size_t)(row0 + 8 * ty + i) * 64 + cc[j]], acc[i][j]);
}

// s[i] = relu(T3[i,:] @ w_gcn1) . w_edge[0:64]   (one wave per row; w1 cached in LDS)
__global__ __launch_bounds__(256) void k_head(const double* __restrict__ T3, const float* __restrict__ w1,
                       const float* __restrict__ we, double* __restrict__ s) {
    __shared__ float w1s[64 * 64];
    int tt = threadIdx.x;
    for (int i = tt; i < 64 * 64; i += 256) w1s[i] = w1[i];
    __syncthreads();
    int row = (blockIdx.x * 256 + tt) >> 6;
    int e = tt & 63;
    const double* r = T3 + (size_t)row * 64;
    double h = 0.0;
#pragma unroll
    for (int c = 0; c < 64; ++c)
        h += r[c] * (double)w1s[c * 64 + e];
    double p = (h > 0.0 ? h : 0.0) * (double)we[e];
    for (int off = 32; off; off >>= 1) p += __shfl_down(p, off, 64);
    if (e == 0) s[row] = p;
}

// Full sort of 4096 keys (desc, idx asc on ties) via packed-u64 register bitonic.
__global__ __launch_bounds__(1024) void k_sort3(const double* __restrict__ s, int* __restrict__ order,
                        double* __restrict__ skey, int* __restrict__ orderB) {
    __shared__ unsigned long long P[NPOOL];   // 32 KB
    __shared__ int idxF[NPOOL];               // 16 KB (fallback only)
    __shared__ int fbS;
    int t = threadIdx.x;
    if (t == 0) fbS = 0;
    unsigned long long v[4];
#pragma unroll
    for (int i = 0; i < 4; ++i) {
        int e = 4 * t + i;
        unsigned long long srt = sortable_u64(s[e]);
        v[i] = ((~(srt >> 12)) << 12) | (unsigned long long)e;
    }

#define SHFL_ROUND(jj, kk)                                                        \
    {                                                                             \
        int lm = (int)((jj) >> 2);                                                \
        _Pragma("unroll")                                                         \
        for (int i = 0; i < 4; ++i) {                                             \
            unsigned long long p = (unsigned long long)__shfl_xor((long long)v[i], lm, 64); \
            unsigned e = 4u * (unsigned)t + (unsigned)i;                          \
            bool takeMin = (((e & (jj)) == 0u) == ((e & (kk)) == 0u));            \
            unsigned long long mn = v[i] < p ? v[i] : p;                          \
            unsigned long long mx = v[i] < p ? p : v[i];                          \
            v[i] = takeMin ? mn : mx;                                             \
        }                                                                         \
    }

#define LOCAL_ROUNDS(kk)                                                          \
    {                                                                             \
        if ((kk) >= 4) {                                                          \
            _Pragma("unroll")                                                     \
            for (int i = 0; i < 2; ++i) {                                         \
                unsigned e = 4u * (unsigned)t + (unsigned)i;                      \
                bool asc = ((e & (kk)) == 0u);                                    \
                unsigned long long a = v[i], b = v[i + 2];                        \
                bool sw = asc ? (a > b) : (a < b);                                \
                v[i] = sw ? b : a; v[i + 2] = sw ? a : b;                         \
            }                                                                     \
        }                                                                         \
        _Pragma("unroll")                                                         \
        for (int i = 0; i < 4; i += 2) {                                          \
            unsigned e = 4u * (unsigned)t + (unsigned)i;                          \
            bool asc = ((e & (kk)) == 0u);                                        \
            unsigned long long a = v[i], b = v[i + 1];                            \
            bool sw = asc ? (a > b) : (a < b);                                    \
            v[i] = sw ? b : a; v[i + 1] = sw ? a : b;                             \
        }                                                                         \
    }

    // phase 1: k = 2..256 (purely intra-wave)
    for (unsigned k = 2; k <= 256; k <<= 1) {
        for (unsigned j = k >> 1; j >= 4; j >>= 1) SHFL_ROUND(j, k)
        LOCAL_ROUNDS(k)
    }
    // phase 2: k = 512..4096 (j>=256 via LDS, rest intra-wave)
    for (unsigned k = 512; k <= 4096; k <<= 1) {
        for (unsigned j = k >> 1; j >= 256; j >>= 1) {
            __syncthreads();
            P[4 * t + 0] = v[0]; P[4 * t + 1] = v[1];
            P[4 * t + 2] = v[2]; P[4 * t + 3] = v[3];
            __syncthreads();
            unsigned base = (4u * (unsigned)t) ^ j;
#pragma unroll
            for (int i = 0; i < 4; ++i) {
                unsigned e = 4u * (unsigned)t + (unsigned)i;
                unsigned long long p = P[base + i];
                bool takeMin = (((e & j) == 0u) == ((e & k) == 0u));
                unsigned long long mn = v[i] < p ? v[i] : p;
                unsigned long long mx = v[i] < p ? p : v[i];
                v[i] = takeMin ? mn : mx;
            }
        }
        for (unsigned j = 128; j >= 4; j >>= 1) SHFL_ROUND(j, k)
        LOCAL_ROUNDS(k)
    }
#undef SHFL_ROUND
#undef LOCAL_ROUNDS

    __syncthreads();
    P[4 * t + 0] = v[0]; P[4 * t + 1] = v[1];
    P[4 * t + 2] = v[2]; P[4 * t + 3] = v[3];
    __syncthreads();
    // truncation-tie guard over positions 0..512 (adjacent pairs)
    if (t < 512) {
        unsigned long long pa = P[t], pb = P[t + 1];
        if ((pa >> 12) == (pb >> 12)) {
            int ia = (int)(pa & 4095ULL), ib = (int)(pb & 4095ULL);
            if (sortable_u64(s[ia]) != sortable_u64(s[ib])) atomicOr(&fbS, 1);
        }
    }
    __syncthreads();
    if (fbS == 0) {
        if (t < NSEQ) {
            int id = (int)(P[t] & 4095ULL);
            order[t] = id; skey[t] = s[id]; orderB[t] = (int)(P[0] & 4095ULL);
        }
        return;
    }
    // exact fallback: full bitonic on (sortable64, idx)
    for (int i = t; i < NPOOL; i += 1024) { P[i] = sortable_u64(s[i]); idxF[i] = i; }
    __syncthreads();
    for (int k2 = 2; k2 <= NPOOL; k2 <<= 1) {
        for (int j = k2 >> 1; j > 0; j >>= 1) {
            for (int tt = t; tt < NPOOL; tt += 1024) {
                int l = tt ^ j;
                if (l > tt) {
                    unsigned long long ka = P[tt], kb = P[l];
                    int ia = idxF[tt], ib = idxF[l];
                    bool aBefore = (ka > kb) || (ka == kb && ia < ib);
                    bool asc = ((tt & k2) == 0);
                    if (asc ? !aBefore : aBefore) { P[tt] = kb; P[l] = ka; idxF[tt] = ib; idxF[l] = ia; }
                }
            }
            __syncthreads();
        }
    }
    for (int tt = t; tt < NSEQ; tt += 1024) {
        int id = idxF[tt];
        order[tt] = id; skey[tt] = s[id]; orderB[tt] = idxF[0];
    }
}

// per-k recurrence pieces for BOTH hypotheses (which = blockIdx.x>>9): A uses orderA, B uses orderB
__global__ __launch_bounds__(256) void k_perk2(const double* __restrict__ Fin, const int* __restrict__ orderA,
                       const int* __restrict__ orderBv,
                       const float* __restrict__ w2, const float* __restrict__ wgr, const float* __restrict__ bgr,
                       const float* __restrict__ wga, const float* __restrict__ bga,
                       double* __restrict__ phi_inf, double* __restrict__ phi_pair, double* __restrict__ hlast) {
    const double r2 = 0.70710678118654752440;
    const double r3 = 0.57735026918962576451;
    __shared__ double u[4][64];
    __shared__ double comb[3][64];
    __shared__ double v[3][64];
    __shared__ double hgg[3][2][GDIM];
    int which = blockIdx.x >> 9;
    int k = blockIdx.x & (NSEQ - 1);
    const int* order = which ? orderBv : orderA;
    double* pi = phi_inf  + (size_t)which * NSEQ * GDIM;
    double* pp = phi_pair + (size_t)which * NSEQ * GDIM;
    double* hl = hlast    + (size_t)which * NSEQ * 64;
    int t = threadIdx.x;
    {
        int w = t >> 6, e = t & 63;
        int j = k - 3 + w;
        u[w][e] = (j >= 0) ? Fin[(size_t)order[j] * 64 + e] : 0.0;
    }
    __syncthreads();
    if (t < 192) {
        int w = t >> 6, e = t & 63;
        double dh_km3 = (k - 3 == 0) ? r2 : r3;
        double dh_km2 = (k - 2 == 0) ? r2 : r3;
        double dh_km1 = (k - 1 == 0) ? r2 : r3;
        double outer, c0, c1, c2, c3;
        if (w == 0) {        // v_{k-2} (final form)
            outer = dh_km2; c0 = dh_km3; c1 = dh_km2; c2 = dh_km1; c3 = 0.0;
        } else if (w == 1) { // v_{k-1}^{(k)}
            outer = dh_km1; c0 = 0.0; c1 = dh_km2; c2 = dh_km1; c3 = r2;
        } else {             // v_k^{(k)}
            if (k == 0) { outer = 1.0; c0 = c1 = c2 = 0.0; c3 = 1.0; }
            else        { outer = r2;  c0 = c1 = 0.0; c2 = dh_km1; c3 = r2; }
        }
        comb[w][e] = outer * (c0 * u[0][e] + c1 * u[1][e] + c2 * u[2][e] + c3 * u[3][e]);
    }
    __syncthreads();
    if (t < 192) {
        int w = t >> 6, e = t & 63;
        double acc = 0.0;
#pragma unroll
        for (int j = 0; j < 64; ++j)
            acc += comb[w][j] * (double)w2[j * 64 + e];
        v[w][e] = acc;
    }
    __syncthreads();
    for (int rep = 0; rep < 3; ++rep) {
        int d = t & 127, g = t >> 7;
        const float* W = g ? wga : wgr;
        const float* B = g ? bga : bgr;
        double acc = (double)B[d];
#pragma unroll
        for (int j = 0; j < 64; ++j)
            acc += v[rep][j] * (double)W[j * GDIM + d];
        hgg[rep][g][d] = acc;
    }
    __syncthreads();
    if (t < 128) {
        if (k >= 2) pi[(size_t)(k - 2) * GDIM + t] = hgg[0][0][t] * sigm_d(hgg[0][1][t]);
        double ppv = hgg[2][0][t] * sigm_d(hgg[2][1][t]);
        if (k >= 1) ppv += hgg[1][0][t] * sigm_d(hgg[1][1][t]);
        pp[(size_t)k * GDIM + t] = ppv;
    } else if (t < 192) {
        hl[(size_t)k * 64 + (t - 128)] = v[2][t - 128];
    }
}

// per-dim prefix scan for both hypotheses: hgr[k] = sum_{j<=k-2} phi_inf[j] + phi_pair[k]
__global__ __launch_bounds__(512) void k_scan2(const double* __restrict__ phi_inf, const double* __restrict__ phi_pair,
                       double* __restrict__ hgr) {
    __shared__ double sb[NSEQ];
    int which = blockIdx.x >> 7;
    int d = blockIdx.x & (GDIM - 1), t = threadIdx.x;
    const double* pi = phi_inf  + (size_t)which * NSEQ * GDIM;
    const double* pp = phi_pair + (size_t)which * NSEQ * GDIM;
    double* hg = hgr + (size_t)which * NSEQ * GDIM;
    sb[t] = (t >= 2) ? pi[(size_t)(t - 2) * GDIM + d] : 0.0;
    for (int off = 1; off < NSEQ; off <<= 1) {
        __syncthreads();
        double add = (t >= off) ? sb[t - off] : 0.0;
        __syncthreads();
        sb[t] += add;
    }
    __syncthreads();
    hg[(size_t)t * GDIM + d] = sb[t] + pp[(size_t)t * GDIM + d];
}

// c_k for both hypotheses; one wave per (which, k)
__global__ __launch_bounds__(64) void k_c2(const double* __restrict__ hlast, const double* __restrict__ hgr,
                   const double* __restrict__ seqe, const float* __restrict__ we,
                   double* __restrict__ cA, double* __restrict__ cB) {
    int which = blockIdx.x >> 9;
    int k = blockIdx.x & (NSEQ - 1), j = threadIdx.x;
    const double* hl = hlast + (size_t)which * NSEQ * 64;
    const double* hg = hgr   + (size_t)which * NSEQ * GDIM;
    double* c = which ? cB : cA;
    double ts = 0.0;
    if (k > 0) {
        ts += relu_d(hl[(size_t)(k - 1) * 64 + j]) * (double)we[64 + j];
        ts += relu_d(hg[(size_t)(k - 1) * GDIM + j]) * (double)we[144 + j];
        ts += relu_d(hg[(size_t)(k - 1) * GDIM + 64 + j]) * (double)we[208 + j];
    }
    if (j < 16) ts += relu_d(seqe[(size_t)k * SDIM + j]) * (double)we[128 + j];
    for (int off = 32; off; off >>= 1) ts += __shfl_down(ts, off, 64);
    if (j == 0) c[k] = ts;
}

// block 0: regime A valid iff skey[t]+cA[t] > 0 for all t>=1
// block 1: regime B valid iff skey[1]+cB[k] <= 0 for all k>=1
__global__ __launch_bounds__(512) void k_verify2(const double* __restrict__ skey, const double* __restrict__ cA,
                         const double* __restrict__ cB, int* __restrict__ flagA, int* __restrict__ flagB) {
    __shared__ int bad;
    int t = threadIdx.x;
    if (t == 0) bad = 0;
    __syncthreads();
    if (blockIdx.x == 0) {
        if (t >= 1 && !(skey[t] + cA[t] > 0.0)) atomicOr(&bad, 1);
        __syncthreads();
        if (t == 0) flagA[0] = bad;
    } else {
        if (t >= 1 && (skey[1] + cB[t] > 0.0)) atomicOr(&bad, 1);
        __syncthreads();
        if (t == 0) flagB[0] = bad;
    }
}

// pick regime: mode 0 = advance (A), 1 = repeat (B), 2 = fallback
__global__ __launch_bounds__(512) void k_select(const int* __restrict__ flagA, const int* __restrict__ flagB,
                        const double* __restrict__ cA, const double* __restrict__ cB,
                        const int* __restrict__ order, double* __restrict__ c,
                        int* __restrict__ idxs_sel, int* __restrict__ mode) {
    int t = threadIdx.x;
    if (flagA[0] == 0) {
        c[t] = cA[t]; idxs_sel[t] = order[t];
        if (t == 0) mode[0] = 0;
    } else if (flagB[0] == 0) {
        c[t] = cB[t]; idxs_sel[t] = order[0];
        if (t == 0) mode[0] = 1;
    } else {
        if (t == 0) mode[0] = 2;
    }
}

// exact sequential fallback (runs only when both fast paths invalid)
__global__ __launch_bounds__(256) void k_fallback(const int* __restrict__ mode,
        const double* __restrict__ Fin, const int* __restrict__ order, const double* __restrict__ skey,
        const double* __restrict__ seqe,
        const float* __restrict__ w2, const float* __restrict__ wgr, const float* __restrict__ bgr,
        const float* __restrict__ wga, const float* __restrict__ bga, const float* __restrict__ we,
        int* __restrict__ idxs_sel, double* __restrict__ c) {
    if (mode[0] != 2) return;
    const double r2 = 0.70710678118654752440;
    const double r3 = 0.57735026918962576451;
    __shared__ double u[4][64];
    __shared__ double comb[3][64];
    __shared__ double v[3][64];
    __shared__ double hgg[3][2][GDIM];
    __shared__ double Phi[GDIM], hgraph[GDIM], hlastS[64];
    __shared__ int selS, ptrS, minS_;
    int t = threadIdx.x;
    if (t < 64) { u[0][t] = u[1][t] = u[2][t] = u[3][t] = 0.0; hlastS[t] = 0.0; }
    if (t < 128) { Phi[t] = 0.0; hgraph[t] = 0.0; }
    if (t == 0) { ptrS = 0; minS_ = 0x7fffffff; }
    __syncthreads();
    for (int k = 0; k < NSEQ; ++k) {
        if (t < 64) {
            int j = t;
            double ts = relu_d(hlastS[j]) * (double)we[64 + j]
                      + relu_d(hgraph[j]) * (double)we[144 + j]
                      + relu_d(hgraph[64 + j]) * (double)we[208 + j];
            if (j < 16) ts += relu_d(seqe[(size_t)k * SDIM + j]) * (double)we[128 + j];
            for (int off = 32; off; off >>= 1) ts += __shfl_down(ts, off, 64);
            if (j == 0) {
                c[k] = ts;
                int ptr = ptrS, idx;
                if (ptr == 0) { idx = order[0]; minS_ = idx; ptrS = 1; }
                else if (skey[ptr] + ts > 0.0) {
                    idx = order[ptr];
                    if (idx < minS_) minS_ = idx;
                    ptrS = ptr + 1;
                } else idx = minS_;
                selS = idx;
                idxs_sel[k] = idx;
            }
        }
        __syncthreads();
        int idx = selS;
        if (t < 64) u[k & 3][t] = Fin[(size_t)idx * 64 + t];
        __syncthreads();
        if (t < 192) {
            int w = t >> 6, e = t & 63;
            double dh_km3 = (k - 3 == 0) ? r2 : r3;
            double dh_km2 = (k - 2 == 0) ? r2 : r3;
            double dh_km1 = (k - 1 == 0) ? r2 : r3;
            double outer, c0, c1, c2, c3;
            if (w == 0) {
                outer = dh_km2; c0 = dh_km3; c1 = dh_km2; c2 = dh_km1; c3 = 0.0;
            } else if (w == 1) {
                outer = dh_km1; c0 = 0.0; c1 = dh_km2; c2 = dh_km1; c3 = r2;
            } else {
                if (k == 0) { outer = 1.0; c0 = c1 = c2 = 0.0; c3 = 1.0; }
                else        { outer = r2;  c0 = c1 = 0.0; c2 = dh_km1; c3 = r2; }
            }
            double uu0 = u[(k - 3) & 3][e], uu1 = u[(k - 2) & 3][e], uu2 = u[(k - 1) & 3][e], uu3 = u[k & 3][e];
            comb[w][e] = outer * (c0 * uu0 + c1 * uu1 + c2 * uu2 + c3 * uu3);
        }
        __syncthreads();
        if (t < 192) {
            int w = t >> 6, e = t & 63;
            double acc = 0.0;
#pragma unroll
            for (int j = 0; j < 64; ++j)
                acc += comb[w][j] * (double)w2[j * 64 + e];
            v[w][e] = acc;
        }
        __syncthreads();
        for (int rep = 0; rep < 3; ++rep) {
            int d = t & 127, g = t >> 7;
            const float* W = g ? wga : wgr;
            const float* B = g ? bga : bgr;
            double acc = (double)B[d];
#pragma unroll
            for (int j = 0; j < 64; ++j)
                acc += v[rep][j] * (double)W[j * GDIM + d];
            hgg[rep][g][d] = acc;
        }
        __syncthreads();
        if (t < 128) {
            if (k >= 2) Phi[t] += hgg[0][0][t] * sigm_d(hgg[0][1][t]);
            double hg = Phi[t] + hgg[2][0][t] * sigm_d(hgg[2][1][t]);
            if (k >= 1) hg += hgg[1][0][t] * sigm_d(hgg[1][1][t]);
            hgraph[t] = hg;
        } else if (t < 192) {
            hlastS[t - 128] = v[2][t - 128];
        }
        __syncthreads();
    }
}

__global__ __launch_bounds__(256) void k_rank_set(const int* __restrict__ idxs_sel, int* __restrict__ rank,
                           float* __restrict__ out) {
    int t = blockIdx.x * 256 + threadIdx.x;
    if (t < NSEQ) {
        atomicMin(&rank[idxs_sel[t]], t);
        out[(size_t)NSEQ * NPOOL + t] = (float)idxs_sel[t];
    }
}

__global__ __launch_bounds__(256) void k_fill(const double* __restrict__ s, const double* __restrict__ c,
                       const int* __restrict__ rank, const float* __restrict__ be, float* __restrict__ out) {
    size_t t = (size_t)blockIdx.x * 256 + threadIdx.x;   // NSEQ*NPOOL
    int k = (int)(t >> 12);
    int i = (int)(t & 4095);
    double bed = (double)be[0];
    bool masked = rank[i] < k;
    out[t] = masked ? (float)bed : (float)(s[i] + c[k] + bed);
}

extern "C" void kernel_launch(void* const* d_in, const int* in_sizes, int n_in,
                              void* d_out, int out_size, void* d_ws, size_t ws_size,
                              hipStream_t stream) {
    const float* x    = (const float*)d_in[0];
    const float* f    = (const float*)d_in[1];
    const float* amat = (const float*)d_in[2];
    const float* dmat = (const float*)d_in[3];
    const float* wf   = (const float*)d_in[4];
    const float* bf   = (const float*)d_in[5];
    const float* w1   = (const float*)d_in[6];
    const float* w2   = (const float*)d_in[7];
    const float* wgr  = (const float*)d_in[8];
    const float* bgr  = (const float*)d_in[9];
    const float* wga  = (const float*)d_in[10];
    const float* bga  = (const float*)d_in[11];
    const float* we   = (const float*)d_in[12];
    const float* be   = (const float*)d_in[13];
    const float* wsq  = (const float*)d_in[14];
    const float* bsq  = (const float*)d_in[15];
    float* out = (float*)d_out;

    char* p = (char*)d_ws;
    const size_t BIG = (size_t)NPOOL * 64 * sizeof(double);   // 2 MB
    double* R    = (double*)p; p += BIG;
    double* Fin  = (double*)p; p += BIG;
    double* T1   = (double*)p; p += BIG;
    double* T2   = (double*)p; p += BIG;
    double* T3   = (double*)p; p += BIG;
    double* seqe = (double*)p; p += (size_t)NSEQ * SDIM * sizeof(double);
    double* s    = (double*)p; p += (size_t)NPOOL * sizeof(double);
    double* skey = (double*)p; p += (size_t)NSEQ * sizeof(double);
    double* phi_inf  = (double*)p; p += 2 * (size_t)NSEQ * GDIM * sizeof(double);
    double* phi_pair = (double*)p; p += 2 * (size_t)NSEQ * GDIM * sizeof(double);
    double* hgr   = (double*)p; p += 2 * (size_t)NSEQ * GDIM * sizeof(double);
    double* hlast = (double*)p; p += 2 * (size_t)NSEQ * 64 * sizeof(double);
    double* cA    = (double*)p; p += (size_t)NSEQ * sizeof(double);
    double* cB    = (double*)p; p += (size_t)NSEQ * sizeof(double);
    double* c     = (double*)p; p += (size_t)NSEQ * sizeof(double);
    int* order    = (int*)p; p += 2048;
    int* orderB   = (int*)p; p += 2048;
    int* idxs_sel = (int*)p; p += 2048;
    int* rank     = (int*)p; p += (size_t)NPOOL * sizeof(int);
    int* flagA    = (int*)p; p += 256;
    int* flagB    = (int*)p; p += 256;
    int* mode     = (int*)p; p += 256;

    dim3 ggrid(NPOOL / 128, SPLITK);   // 32 x 16 = 512 blocks

    k_prep<<<1024, 256, 0, stream>>>(f, wf, bf, Fin, R, T1, T2, T3);  // also zeroes T1,T2,T3
    k_seqe<<<32, 256, 0, stream>>>(x, wsq, bsq, seqe, rank);          // also inits rank

    gemm_f64_v7<<<ggrid, 256, 0, stream>>>(dmat, R, T1);    // t1 = d @ R
    gemm_f64_v7<<<ggrid, 256, 0, stream>>>(amat, T1, T2);   // t2 = a @ t1
    gemm_f64_v7<<<ggrid, 256, 0, stream>>>(dmat, T2, T3);   // t3 = d @ t2

    k_head<<<NPOOL / 4, 256, 0, stream>>>(T3, w1, we, s);
    k_sort3<<<1, 1024, 0, stream>>>(s, order, skey, orderB);

    // both hypotheses fused (A: sorted order; B: repeat order[0])
    k_perk2<<<2 * NSEQ, 256, 0, stream>>>(Fin, order, orderB, w2, wgr, bgr, wga, bga, phi_inf, phi_pair, hlast);
    k_scan2<<<2 * GDIM, 512, 0, stream>>>(phi_inf, phi_pair, hgr);
    k_c2<<<2 * NSEQ, 64, 0, stream>>>(hlast, hgr, seqe, we, cA, cB);
    k_verify2<<<2, 512, 0, stream>>>(skey, cA, cB, flagA, flagB);

    k_select<<<1, 512, 0, stream>>>(flagA, flagB, cA, cB, order, c, idxs_sel, mode);
    k_fallback<<<1, 256, 0, stream>>>(mode, Fin, order, skey, seqe, w2, wgr, bgr, wga, bga, we, idxs_sel, c);

    k_rank_set<<<2, 256, 0, stream>>>(idxs_sel, rank, out);
    k_fill<<<(NSEQ * NPOOL) / 256, 256, 0, stream>>>(s, c, rank, be, out);
}

// Round 8
// 619.876 us; speedup vs baseline: 3.4167x; 3.4167x over previous
//
#include <hip/hip_runtime.h>
#include <math.h>

#define NPOOL 4096
#define NSEQ  512
#define NF    20
#define EDIM  64
#define GDIM  128
#define SDIM  16
#define ALPH  20
#define SPLITK 32
#define KSLICE (NPOOL / SPLITK)   // 128

__device__ __forceinline__ double relu_d(double x){ return x > 0.0 ? x : 0.0; }
__device__ __forceinline__ double sigm_d(double x){ return 1.0 / (1.0 + exp(-x)); }

__device__ __forceinline__ unsigned long long sortable_u64(double x) {
    x = x + 0.0;                                  // canonicalize -0 -> +0
    unsigned long long b = (unsigned long long)__double_as_longlong(x);
    return b ^ ((b >> 63) ? ~0ULL : 0x8000000000000000ULL);
}

// Fin[i][e] = f @ w_feat + b_feat (f64); R = relu(Fin). Also zeroes T1,T2,T3.
__global__ __launch_bounds__(256) void k_prep(const float* __restrict__ f, const float* __restrict__ wf,
                       const float* __restrict__ bf, double* __restrict__ Fin, double* __restrict__ R,
                       double* __restrict__ T1z, double* __restrict__ T2z, double* __restrict__ T3z) {
    int t = blockIdx.x * 256 + threadIdx.x;   // NPOOL*EDIM
    int i = t >> 6, e = t & 63;
    double acc = (double)bf[e];
#pragma unroll
    for (int j = 0; j < NF; ++j)
        acc += (double)f[i * NF + j] * (double)wf[j * EDIM + e];
    Fin[t] = acc;
    R[t] = acc > 0.0 ? acc : 0.0;
    T1z[t] = 0.0; T2z[t] = 0.0; T3z[t] = 0.0;
}

// seq_embed = x @ w_seq + b_seq (f64). Also inits rank[].
__global__ __launch_bounds__(256) void k_seqe(const float* __restrict__ x, const float* __restrict__ wsq,
                       const float* __restrict__ bsq, double* __restrict__ seqe, int* __restrict__ rank) {
    int t = blockIdx.x * 256 + threadIdx.x;   // NSEQ*SDIM = 8192
    int k = t >> 4, s = t & 15;
    double acc = (double)bsq[s];
#pragma unroll
    for (int q = 0; q < ALPH; ++q)
        acc += (double)x[k * ALPH + q] * (double)wsq[q * SDIM + s];
    seqe[t] = acc;
    if (t < NPOOL) rank[t] = 1 << 30;
}

// C(4096x64 f64) += A(4096x4096 f32) @ B(4096x64 f64), split-K, VALU f64 FMA.
// v8 = v7's verified layout WITHOUT register staging (v7 passed correctness; spills killed it).
// 128x64 block, 256 threads (16tx x 16ty), thread = rows 8ty..8ty+7 x cols {2tx,2tx+1,2tx+32,2tx+33}.
// A stored f32 in LDS (A input IS f32 -> exact): per kk 2 f32-b128 (A) + 2 f64-b128 (B)
// per 32 MACs = half of v3's LDS reads/MAC. A-read: 16-lane broadcast (free).
// B-read: 2-way (free). A-write swizzle rs = r ^ (kq<<2): 16 distinct banks/quarter-wave.
// Read un-swizzle: abase = 8*(ty ^ (kqr>>1)), lo/hi swap when kqr&1 (compile-time, kk unrolled).
// SPLITK 32 -> grid 32x32 = 1024 blocks = 4 resident/CU (33.8 KB LDS), same atomic count as v3.
__global__ __launch_bounds__(256, 4) void gemm_f64_v8(const float* __restrict__ A, const double* __restrict__ B,
                                                      double* __restrict__ C) {
    __shared__ float  As[32][132];   // [k][row-slot swizzled], f32
    __shared__ double Bs[32][66];    // [k][col]
    int t  = threadIdx.x;
    int tx = t & 15;
    int ty = t >> 4;
    int row0 = blockIdx.x * 128;
    int k0   = blockIdx.y * KSLICE;
    int kq = t & 3, kb = kq << 3;    // staging: this thread covers k = kb..kb+7
    int ar = t >> 2;                 // staging A row (0..63; +64 for second half)

    double acc[8][4] = {};

    for (int kt = k0; kt < k0 + KSLICE; kt += 32) {
        // stage A: 128 rows x 32 k, f32, swizzled slots (direct, transient regs only)
#pragma unroll
        for (int h = 0; h < 2; ++h) {
            const float* Ap = A + (size_t)(row0 + ar + 64 * h) * NPOOL + kt + kq * 8;
            float4 f0 = *(const float4*)Ap;
            float4 f1 = *(const float4*)(Ap + 4);
            int rs = (ar + 64 * h) ^ (kq << 2);
            As[kb + 0][rs] = f0.x; As[kb + 1][rs] = f0.y;
            As[kb + 2][rs] = f0.z; As[kb + 3][rs] = f0.w;
            As[kb + 4][rs] = f1.x; As[kb + 5][rs] = f1.y;
            As[kb + 6][rs] = f1.z; As[kb + 7][rs] = f1.w;
        }
        // stage B: 32 k-rows x 64 cols (double2)
#pragma unroll
        for (int it = 0; it < 4; ++it) {
            int e = 2 * t + 512 * it;
            *(double2*)&Bs[e >> 6][e & 63] = *(const double2*)&B[(size_t)(kt + (e >> 6)) * 64 + (e & 63)];
        }
        __syncthreads();
#pragma unroll
        for (int kk = 0; kk < 32; ++kk) {
            const int kqr = kk >> 3;
            int abase = 8 * (ty ^ (kqr >> 1));
            float4 alo = *(const float4*)&As[kk][abase];
            float4 ahi = *(const float4*)&As[kk][abase + 4];
            if (kqr & 1) { float4 tmp = alo; alo = ahi; ahi = tmp; }  // compile-time
            double a[8] = {(double)alo.x, (double)alo.y, (double)alo.z, (double)alo.w,
                           (double)ahi.x, (double)ahi.y, (double)ahi.z, (double)ahi.w};
            double2 b01 = *(const double2*)&Bs[kk][2 * tx];
            double2 b23 = *(const double2*)&Bs[kk][2 * tx + 32];
            double b[4] = {b01.x, b01.y, b23.x, b23.y};
#pragma unroll
            for (int i = 0; i < 8; ++i)
#pragma unroll
                for (int j = 0; j < 4; ++j)
                    acc[i][j] = fma(a[i], b[j], acc[i][j]);
        }
        __syncthreads();
    }

    int cc[4] = {2 * tx, 2 * tx + 1, 2 * tx + 32, 2 * tx + 33};
#pragma unroll
    for (int i = 0; i < 8; ++i)
#pragma unroll
        for (int j = 0; j < 4; ++j)
            unsafeAtomicAdd(&C[(size_t)(row0 + 8 * ty + i) * 64 + cc[j]], acc[i][j]);
}

// s[i] = relu(T3[i,:] @ w_gcn1) . w_edge[0:64]   (one wave per row; w1 cached in LDS)
__global__ __launch_bounds__(256) void k_head(const double* __restrict__ T3, const float* __restrict__ w1,
                       const float* __restrict__ we, double* __restrict__ s) {
    __shared__ float w1s[64 * 64];
    int tt = threadIdx.x;
    for (int i = tt; i < 64 * 64; i += 256) w1s[i] = w1[i];
    __syncthreads();
    int row = (blockIdx.x * 256 + tt) >> 6;
    int e = tt & 63;
    const double* r = T3 + (size_t)row * 64;
    double h = 0.0;
#pragma unroll
    for (int c = 0; c < 64; ++c)
        h += r[c] * (double)w1s[c * 64 + e];
    double p = (h > 0.0 ? h : 0.0) * (double)we[e];
    for (int off = 32; off; off >>= 1) p += __shfl_down(p, off, 64);
    if (e == 0) s[row] = p;
}

// Full sort of 4096 keys (desc, idx asc on ties) via packed-u64 register bitonic.
__global__ __launch_bounds__(1024) void k_sort3(const double* __restrict__ s, int* __restrict__ order,
                        double* __restrict__ skey, int* __restrict__ orderB) {
    __shared__ unsigned long long P[NPOOL];   // 32 KB
    __shared__ int idxF[NPOOL];               // 16 KB (fallback only)
    __shared__ int fbS;
    int t = threadIdx.x;
    if (t == 0) fbS = 0;
    unsigned long long v[4];
#pragma unroll
    for (int i = 0; i < 4; ++i) {
        int e = 4 * t + i;
        unsigned long long srt = sortable_u64(s[e]);
        v[i] = ((~(srt >> 12)) << 12) | (unsigned long long)e;
    }

#define SHFL_ROUND(jj, kk)                                                        \
    {                                                                             \
        int lm = (int)((jj) >> 2);                                                \
        _Pragma("unroll")                                                         \
        for (int i = 0; i < 4; ++i) {                                             \
            unsigned long long p = (unsigned long long)__shfl_xor((long long)v[i], lm, 64); \
            unsigned e = 4u * (unsigned)t + (unsigned)i;                          \
            bool takeMin = (((e & (jj)) == 0u) == ((e & (kk)) == 0u));            \
            unsigned long long mn = v[i] < p ? v[i] : p;                          \
            unsigned long long mx = v[i] < p ? p : v[i];                          \
            v[i] = takeMin ? mn : mx;                                             \
        }                                                                         \
    }

#define LOCAL_ROUNDS(kk)                                                          \
    {                                                                             \
        if ((kk) >= 4) {                                                          \
            _Pragma("unroll")                                                     \
            for (int i = 0; i < 2; ++i) {                                         \
                unsigned e = 4u * (unsigned)t + (unsigned)i;                      \
                bool asc = ((e & (kk)) == 0u);                                    \
                unsigned long long a = v[i], b = v[i + 2];                        \
                bool sw = asc ? (a > b) : (a < b);                                \
                v[i] = sw ? b : a; v[i + 2] = sw ? a : b;                         \
            }                                                                     \
        }                                                                         \
        _Pragma("unroll")                                                         \
        for (int i = 0; i < 4; i += 2) {                                          \
            unsigned e = 4u * (unsigned)t + (unsigned)i;                          \
            bool asc = ((e & (kk)) == 0u);                                        \
            unsigned long long a = v[i], b = v[i + 1];                            \
            bool sw = asc ? (a > b) : (a < b);                                    \
            v[i] = sw ? b : a; v[i + 1] = sw ? a : b;                             \
        }                                                                         \
    }

    // phase 1: k = 2..256 (purely intra-wave)
    for (unsigned k = 2; k <= 256; k <<= 1) {
        for (unsigned j = k >> 1; j >= 4; j >>= 1) SHFL_ROUND(j, k)
        LOCAL_ROUNDS(k)
    }
    // phase 2: k = 512..4096 (j>=256 via LDS, rest intra-wave)
    for (unsigned k = 512; k <= 4096; k <<= 1) {
        for (unsigned j = k >> 1; j >= 256; j >>= 1) {
            __syncthreads();
            P[4 * t + 0] = v[0]; P[4 * t + 1] = v[1];
            P[4 * t + 2] = v[2]; P[4 * t + 3] = v[3];
            __syncthreads();
            unsigned base = (4u * (unsigned)t) ^ j;
#pragma unroll
            for (int i = 0; i < 4; ++i) {
                unsigned e = 4u * (unsigned)t + (unsigned)i;
                unsigned long long p = P[base + i];
                bool takeMin = (((e & j) == 0u) == ((e & k) == 0u));
                unsigned long long mn = v[i] < p ? v[i] : p;
                unsigned long long mx = v[i] < p ? p : v[i];
                v[i] = takeMin ? mn : mx;
            }
        }
        for (unsigned j = 128; j >= 4; j >>= 1) SHFL_ROUND(j, k)
        LOCAL_ROUNDS(k)
    }
#undef SHFL_ROUND
#undef LOCAL_ROUNDS

    __syncthreads();
    P[4 * t + 0] = v[0]; P[4 * t + 1] = v[1];
    P[4 * t + 2] = v[2]; P[4 * t + 3] = v[3];
    __syncthreads();
    // truncation-tie guard over positions 0..512 (adjacent pairs)
    if (t < 512) {
        unsigned long long pa = P[t], pb = P[t + 1];
        if ((pa >> 12) == (pb >> 12)) {
            int ia = (int)(pa & 4095ULL), ib = (int)(pb & 4095ULL);
            if (sortable_u64(s[ia]) != sortable_u64(s[ib])) atomicOr(&fbS, 1);
        }
    }
    __syncthreads();
    if (fbS == 0) {
        if (t < NSEQ) {
            int id = (int)(P[t] & 4095ULL);
            order[t] = id; skey[t] = s[id]; orderB[t] = (int)(P[0] & 4095ULL);
        }
        return;
    }
    // exact fallback: full bitonic on (sortable64, idx)
    for (int i = t; i < NPOOL; i += 1024) { P[i] = sortable_u64(s[i]); idxF[i] = i; }
    __syncthreads();
    for (int k2 = 2; k2 <= NPOOL; k2 <<= 1) {
        for (int j = k2 >> 1; j > 0; j >>= 1) {
            for (int tt = t; tt < NPOOL; tt += 1024) {
                int l = tt ^ j;
                if (l > tt) {
                    unsigned long long ka = P[tt], kb = P[l];
                    int ia = idxF[tt], ib = idxF[l];
                    bool aBefore = (ka > kb) || (ka == kb && ia < ib);
                    bool asc = ((tt & k2) == 0);
                    if (asc ? !aBefore : aBefore) { P[tt] = kb; P[l] = ka; idxF[tt] = ib; idxF[l] = ia; }
                }
            }
            __syncthreads();
        }
    }
    for (int tt = t; tt < NSEQ; tt += 1024) {
        int id = idxF[tt];
        order[tt] = id; skey[tt] = s[id]; orderB[tt] = idxF[0];
    }
}

// per-k recurrence pieces for BOTH hypotheses (which = blockIdx.x>>9): A uses orderA, B uses orderB
__global__ __launch_bounds__(256) void k_perk2(const double* __restrict__ Fin, const int* __restrict__ orderA,
                       const int* __restrict__ orderBv,
                       const float* __restrict__ w2, const float* __restrict__ wgr, const float* __restrict__ bgr,
                       const float* __restrict__ wga, const float* __restrict__ bga,
                       double* __restrict__ phi_inf, double* __restrict__ phi_pair, double* __restrict__ hlast) {
    const double r2 = 0.70710678118654752440;
    const double r3 = 0.57735026918962576451;
    __shared__ double u[4][64];
    __shared__ double comb[3][64];
    __shared__ double v[3][64];
    __shared__ double hgg[3][2][GDIM];
    int which = blockIdx.x >> 9;
    int k = blockIdx.x & (NSEQ - 1);
    const int* order = which ? orderBv : orderA;
    double* pi = phi_inf  + (size_t)which * NSEQ * GDIM;
    double* pp = phi_pair + (size_t)which * NSEQ * GDIM;
    double* hl = hlast    + (size_t)which * NSEQ * 64;
    int t = threadIdx.x;
    {
        int w = t >> 6, e = t & 63;
        int j = k - 3 + w;
        u[w][e] = (j >= 0) ? Fin[(size_t)order[j] * 64 + e] : 0.0;
    }
    __syncthreads();
    if (t < 192) {
        int w = t >> 6, e = t & 63;
        double dh_km3 = (k - 3 == 0) ? r2 : r3;
        double dh_km2 = (k - 2 == 0) ? r2 : r3;
        double dh_km1 = (k - 1 == 0) ? r2 : r3;
        double outer, c0, c1, c2, c3;
        if (w == 0) {        // v_{k-2} (final form)
            outer = dh_km2; c0 = dh_km3; c1 = dh_km2; c2 = dh_km1; c3 = 0.0;
        } else if (w == 1) { // v_{k-1}^{(k)}
            outer = dh_km1; c0 = 0.0; c1 = dh_km2; c2 = dh_km1; c3 = r2;
        } else {             // v_k^{(k)}
            if (k == 0) { outer = 1.0; c0 = c1 = c2 = 0.0; c3 = 1.0; }
            else        { outer = r2;  c0 = c1 = 0.0; c2 = dh_km1; c3 = r2; }
        }
        comb[w][e] = outer * (c0 * u[0][e] + c1 * u[1][e] + c2 * u[2][e] + c3 * u[3][e]);
    }
    __syncthreads();
    if (t < 192) {
        int w = t >> 6, e = t & 63;
        double acc = 0.0;
#pragma unroll
        for (int j = 0; j < 64; ++j)
            acc += comb[w][j] * (double)w2[j * 64 + e];
        v[w][e] = acc;
    }
    __syncthreads();
    for (int rep = 0; rep < 3; ++rep) {
        int d = t & 127, g = t >> 7;
        const float* W = g ? wga : wgr;
        const float* B = g ? bga : bgr;
        double acc = (double)B[d];
#pragma unroll
        for (int j = 0; j < 64; ++j)
            acc += v[rep][j] * (double)W[j * GDIM + d];
        hgg[rep][g][d] = acc;
    }
    __syncthreads();
    if (t < 128) {
        if (k >= 2) pi[(size_t)(k - 2) * GDIM + t] = hgg[0][0][t] * sigm_d(hgg[0][1][t]);
        double ppv = hgg[2][0][t] * sigm_d(hgg[2][1][t]);
        if (k >= 1) ppv += hgg[1][0][t] * sigm_d(hgg[1][1][t]);
        pp[(size_t)k * GDIM + t] = ppv;
    } else if (t < 192) {
        hl[(size_t)k * 64 + (t - 128)] = v[2][t - 128];
    }
}

// per-dim prefix scan for both hypotheses: hgr[k] = sum_{j<=k-2} phi_inf[j] + phi_pair[k]
__global__ __launch_bounds__(512) void k_scan2(const double* __restrict__ phi_inf, const double* __restrict__ phi_pair,
                       double* __restrict__ hgr) {
    __shared__ double sb[NSEQ];
    int which = blockIdx.x >> 7;
    int d = blockIdx.x & (GDIM - 1), t = threadIdx.x;
    const double* pi = phi_inf  + (size_t)which * NSEQ * GDIM;
    const double* pp = phi_pair + (size_t)which * NSEQ * GDIM;
    double* hg = hgr + (size_t)which * NSEQ * GDIM;
    sb[t] = (t >= 2) ? pi[(size_t)(t - 2) * GDIM + d] : 0.0;
    for (int off = 1; off < NSEQ; off <<= 1) {
        __syncthreads();
        double add = (t >= off) ? sb[t - off] : 0.0;
        __syncthreads();
        sb[t] += add;
    }
    __syncthreads();
    hg[(size_t)t * GDIM + d] = sb[t] + pp[(size_t)t * GDIM + d];
}

// c_k for both hypotheses; one wave per (which, k)
__global__ __launch_bounds__(64) void k_c2(const double* __restrict__ hlast, const double* __restrict__ hgr,
                   const double* __restrict__ seqe, const float* __restrict__ we,
                   double* __restrict__ cA, double* __restrict__ cB) {
    int which = blockIdx.x >> 9;
    int k = blockIdx.x & (NSEQ - 1), j = threadIdx.x;
    const double* hl = hlast + (size_t)which * NSEQ * 64;
    const double* hg = hgr   + (size_t)which * NSEQ * GDIM;
    double* c = which ? cB : cA;
    double ts = 0.0;
    if (k > 0) {
        ts += relu_d(hl[(size_t)(k - 1) * 64 + j]) * (double)we[64 + j];
        ts += relu_d(hg[(size_t)(k - 1) * GDIM + j]) * (double)we[144 + j];
        ts += relu_d(hg[(size_t)(k - 1) * GDIM + 64 + j]) * (double)we[208 + j];
    }
    if (j < 16) ts += relu_d(seqe[(size_t)k * SDIM + j]) * (double)we[128 + j];
    for (int off = 32; off; off >>= 1) ts += __shfl_down(ts, off, 64);
    if (j == 0) c[k] = ts;
}

// block 0: regime A valid iff skey[t]+cA[t] > 0 for all t>=1
// block 1: regime B valid iff skey[1]+cB[k] <= 0 for all k>=1
__global__ __launch_bounds__(512) void k_verify2(const double* __restrict__ skey, const double* __restrict__ cA,
                         const double* __restrict__ cB, int* __restrict__ flagA, int* __restrict__ flagB) {
    __shared__ int bad;
    int t = threadIdx.x;
    if (t == 0) bad = 0;
    __syncthreads();
    if (blockIdx.x == 0) {
        if (t >= 1 && !(skey[t] + cA[t] > 0.0)) atomicOr(&bad, 1);
        __syncthreads();
        if (t == 0) flagA[0] = bad;
    } else {
        if (t >= 1 && (skey[1] + cB[t] > 0.0)) atomicOr(&bad, 1);
        __syncthreads();
        if (t == 0) flagB[0] = bad;
    }
}

// pick regime: mode 0 = advance (A), 1 = repeat (B), 2 = fallback
__global__ __launch_bounds__(512) void k_select(const int* __restrict__ flagA, const int* __restrict__ flagB,
                        const double* __restrict__ cA, const double* __restrict__ cB,
                        const int* __restrict__ order, double* __restrict__ c,
                        int* __restrict__ idxs_sel, int* __restrict__ mode) {
    int t = threadIdx.x;
    if (flagA[0] == 0) {
        c[t] = cA[t]; idxs_sel[t] = order[t];
        if (t == 0) mode[0] = 0;
    } else if (flagB[0] == 0) {
        c[t] = cB[t]; idxs_sel[t] = order[0];
        if (t == 0) mode[0] = 1;
    } else {
        if (t == 0) mode[0] = 2;
    }
}

// exact sequential fallback (runs only when both fast paths invalid)
__global__ __launch_bounds__(256) void k_fallback(const int* __restrict__ mode,
        const double* __restrict__ Fin, const int* __restrict__ order, const double* __restrict__ skey,
        const double* __restrict__ seqe,
        const float* __restrict__ w2, const float* __restrict__ wgr, const float* __restrict__ bgr,
        const float* __restrict__ wga, const float* __restrict__ bga, const float* __restrict__ we,
        int* __restrict__ idxs_sel, double* __restrict__ c) {
    if (mode[0] != 2) return;
    const double r2 = 0.70710678118654752440;
    const double r3 = 0.57735026918962576451;
    __shared__ double u[4][64];
    __shared__ double comb[3][64];
    __shared__ double v[3][64];
    __shared__ double hgg[3][2][GDIM];
    __shared__ double Phi[GDIM], hgraph[GDIM], hlastS[64];
    __shared__ int selS, ptrS, minS_;
    int t = threadIdx.x;
    if (t < 64) { u[0][t] = u[1][t] = u[2][t] = u[3][t] = 0.0; hlastS[t] = 0.0; }
    if (t < 128) { Phi[t] = 0.0; hgraph[t] = 0.0; }
    if (t == 0) { ptrS = 0; minS_ = 0x7fffffff; }
    __syncthreads();
    for (int k = 0; k < NSEQ; ++k) {
        if (t < 64) {
            int j = t;
            double ts = relu_d(hlastS[j]) * (double)we[64 + j]
                      + relu_d(hgraph[j]) * (double)we[144 + j]
                      + relu_d(hgraph[64 + j]) * (double)we[208 + j];
            if (j < 16) ts += relu_d(seqe[(size_t)k * SDIM + j]) * (double)we[128 + j];
            for (int off = 32; off; off >>= 1) ts += __shfl_down(ts, off, 64);
            if (j == 0) {
                c[k] = ts;
                int ptr = ptrS, idx;
                if (ptr == 0) { idx = order[0]; minS_ = idx; ptrS = 1; }
                else if (skey[ptr] + ts > 0.0) {
                    idx = order[ptr];
                    if (idx < minS_) minS_ = idx;
                    ptrS = ptr + 1;
                } else idx = minS_;
                selS = idx;
                idxs_sel[k] = idx;
            }
        }
        __syncthreads();
        int idx = selS;
        if (t < 64) u[k & 3][t] = Fin[(size_t)idx * 64 + t];
        __syncthreads();
        if (t < 192) {
            int w = t >> 6, e = t & 63;
            double dh_km3 = (k - 3 == 0) ? r2 : r3;
            double dh_km2 = (k - 2 == 0) ? r2 : r3;
            double dh_km1 = (k - 1 == 0) ? r2 : r3;
            double outer, c0, c1, c2, c3;
            if (w == 0) {
                outer = dh_km2; c0 = dh_km3; c1 = dh_km2; c2 = dh_km1; c3 = 0.0;
            } else if (w == 1) {
                outer = dh_km1; c0 = 0.0; c1 = dh_km2; c2 = dh_km1; c3 = r2;
            } else {
                if (k == 0) { outer = 1.0; c0 = c1 = c2 = 0.0; c3 = 1.0; }
                else        { outer = r2;  c0 = c1 = 0.0; c2 = dh_km1; c3 = r2; }
            }
            double uu0 = u[(k - 3) & 3][e], uu1 = u[(k - 2) & 3][e], uu2 = u[(k - 1) & 3][e], uu3 = u[k & 3][e];
            comb[w][e] = outer * (c0 * uu0 + c1 * uu1 + c2 * uu2 + c3 * uu3);
        }
        __syncthreads();
        if (t < 192) {
            int w = t >> 6, e = t & 63;
            double acc = 0.0;
#pragma unroll
            for (int j = 0; j < 64; ++j)
                acc += comb[w][j] * (double)w2[j * 64 + e];
            v[w][e] = acc;
        }
        __syncthreads();
        for (int rep = 0; rep < 3; ++rep) {
            int d = t & 127, g = t >> 7;
            const float* W = g ? wga : wgr;
            const float* B = g ? bga : bgr;
            double acc = (double)B[d];
#pragma unroll
            for (int j = 0; j < 64; ++j)
                acc += v[rep][j] * (double)W[j * GDIM + d];
            hgg[rep][g][d] = acc;
        }
        __syncthreads();
        if (t < 128) {
            if (k >= 2) Phi[t] += hgg[0][0][t] * sigm_d(hgg[0][1][t]);
            double hg = Phi[t] + hgg[2][0][t] * sigm_d(hgg[2][1][t]);
            if (k >= 1) hg += hgg[1][0][t] * sigm_d(hgg[1][1][t]);
            hgraph[t] = hg;
        } else if (t < 192) {
            hlastS[t - 128] = v[2][t - 128];
        }
        __syncthreads();
    }
}

__global__ __launch_bounds__(256) void k_rank_set(const int* __restrict__ idxs_sel, int* __restrict__ rank,
                           float* __restrict__ out) {
    int t = blockIdx.x * 256 + threadIdx.x;
    if (t < NSEQ) {
        atomicMin(&rank[idxs_sel[t]], t);
        out[(size_t)NSEQ * NPOOL + t] = (float)idxs_sel[t];
    }
}

__global__ __launch_bounds__(256) void k_fill(const double* __restrict__ s, const double* __restrict__ c,
                       const int* __restrict__ rank, const float* __restrict__ be, float* __restrict__ out) {
    size_t t = (size_t)blockIdx.x * 256 + threadIdx.x;   // NSEQ*NPOOL
    int k = (int)(t >> 12);
    int i = (int)(t & 4095);
    double bed = (double)be[0];
    bool masked = rank[i] < k;
    out[t] = masked ? (float)bed : (float)(s[i] + c[k] + bed);
}

extern "C" void kernel_launch(void* const* d_in, const int* in_sizes, int n_in,
                              void* d_out, int out_size, void* d_ws, size_t ws_size,
                              hipStream_t stream) {
    const float* x    = (const float*)d_in[0];
    const float* f    = (const float*)d_in[1];
    const float* amat = (const float*)d_in[2];
    const float* dmat = (const float*)d_in[3];
    const float* wf   = (const float*)d_in[4];
    const float* bf   = (const float*)d_in[5];
    const float* w1   = (const float*)d_in[6];
    const float* w2   = (const float*)d_in[7];
    const float* wgr  = (const float*)d_in[8];
    const float* bgr  = (const float*)d_in[9];
    const float* wga  = (const float*)d_in[10];
    const float* bga  = (const float*)d_in[11];
    const float* we   = (const float*)d_in[12];
    const float* be   = (const float*)d_in[13];
    const float* wsq  = (const float*)d_in[14];
    const float* bsq  = (const float*)d_in[15];
    float* out = (float*)d_out;

    char* p = (char*)d_ws;
    const size_t BIG = (size_t)NPOOL * 64 * sizeof(double);   // 2 MB
    double* R    = (double*)p; p += BIG;
    double* Fin  = (double*)p; p += BIG;
    double* T1   = (double*)p; p += BIG;
    double* T2   = (double*)p; p += BIG;
    double* T3   = (double*)p; p += BIG;
    double* seqe = (double*)p; p += (size_t)NSEQ * SDIM * sizeof(double);
    double* s    = (double*)p; p += (size_t)NPOOL * sizeof(double);
    double* skey = (double*)p; p += (size_t)NSEQ * sizeof(double);
    double* phi_inf  = (double*)p; p += 2 * (size_t)NSEQ * GDIM * sizeof(double);
    double* phi_pair = (double*)p; p += 2 * (size_t)NSEQ * GDIM * sizeof(double);
    double* hgr   = (double*)p; p += 2 * (size_t)NSEQ * GDIM * sizeof(double);
    double* hlast = (double*)p; p += 2 * (size_t)NSEQ * 64 * sizeof(double);
    double* cA    = (double*)p; p += (size_t)NSEQ * sizeof(double);
    double* cB    = (double*)p; p += (size_t)NSEQ * sizeof(double);
    double* c     = (double*)p; p += (size_t)NSEQ * sizeof(double);
    int* order    = (int*)p; p += 2048;
    int* orderB   = (int*)p; p += 2048;
    int* idxs_sel = (int*)p; p += 2048;
    int* rank     = (int*)p; p += (size_t)NPOOL * sizeof(int);
    int* flagA    = (int*)p; p += 256;
    int* flagB    = (int*)p; p += 256;
    int* mode     = (int*)p; p += 256;

    dim3 ggrid(NPOOL / 128, SPLITK);   // 32 x 32 = 1024 blocks

    k_prep<<<1024, 256, 0, stream>>>(f, wf, bf, Fin, R, T1, T2, T3);  // also zeroes T1,T2,T3
    k_seqe<<<32, 256, 0, stream>>>(x, wsq, bsq, seqe, rank);          // also inits rank

    gemm_f64_v8<<<ggrid, 256, 0, stream>>>(dmat, R, T1);    // t1 = d @ R
    gemm_f64_v8<<<ggrid, 256, 0, stream>>>(amat, T1, T2);   // t2 = a @ t1
    gemm_f64_v8<<<ggrid, 256, 0, stream>>>(dmat, T2, T3);   // t3 = d @ t2

    k_head<<<NPOOL / 4, 256, 0, stream>>>(T3, w1, we, s);
    k_sort3<<<1, 1024, 0, stream>>>(s, order, skey, orderB);

    // both hypotheses fused (A: sorted order; B: repeat order[0])
    k_perk2<<<2 * NSEQ, 256, 0, stream>>>(Fin, order, orderB, w2, wgr, bgr, wga, bga, phi_inf, phi_pair, hlast);
    k_scan2<<<2 * GDIM, 512, 0, stream>>>(phi_inf, phi_pair, hgr);
    k_c2<<<2 * NSEQ, 64, 0, stream>>>(hlast, hgr, seqe, we, cA, cB);
    k_verify2<<<2, 512, 0, stream>>>(skey, cA, cB, flagA, flagB);

    k_select<<<1, 512, 0, stream>>>(flagA, flagB, cA, cB, order, c, idxs_sel, mode);
    k_fallback<<<1, 256, 0, stream>>>(mode, Fin, order, skey, seqe, w2, wgr, bgr, wga, bga, we, idxs_sel, c);

    k_rank_set<<<2, 256, 0, stream>>>(idxs_sel, rank, out);
    k_fill<<<(NSEQ * NPOOL) / 256, 256, 0, stream>>>(s, c, rank, be, out);
}

// Round 9
// 469.424 us; speedup vs baseline: 4.5117x; 1.3205x over previous
//
#include <hip/hip_runtime.h>
#include <math.h>

#define NPOOL 4096
#define NSEQ  512
#define NF    20
#define EDIM  64
#define GDIM  128
#define SDIM  16
#define ALPH  20
#define SPLITK 16
#define KSLICE (NPOOL / SPLITK)   // 256

__device__ __forceinline__ double relu_d(double x){ return x > 0.0 ? x : 0.0; }
__device__ __forceinline__ double sigm_d(double x){ return 1.0 / (1.0 + exp(-x)); }

__device__ __forceinline__ unsigned long long sortable_u64(double x) {
    x = x + 0.0;                                  // canonicalize -0 -> +0
    unsigned long long b = (unsigned long long)__double_as_longlong(x);
    return b ^ ((b >> 63) ? ~0ULL : 0x8000000000000000ULL);
}

// Fin[i][e] = f @ w_feat + b_feat (f64); R = relu(Fin). Also zeroes T1,T2,T3.
__global__ __launch_bounds__(256) void k_prep(const float* __restrict__ f, const float* __restrict__ wf,
                       const float* __restrict__ bf, double* __restrict__ Fin, double* __restrict__ R,
                       double* __restrict__ T1z, double* __restrict__ T2z, double* __restrict__ T3z) {
    int t = blockIdx.x * 256 + threadIdx.x;   // NPOOL*EDIM
    int i = t >> 6, e = t & 63;
    double acc = (double)bf[e];
#pragma unroll
    for (int j = 0; j < NF; ++j)
        acc += (double)f[i * NF + j] * (double)wf[j * EDIM + e];
    Fin[t] = acc;
    R[t] = acc > 0.0 ? acc : 0.0;
    T1z[t] = 0.0; T2z[t] = 0.0; T3z[t] = 0.0;
}

// seq_embed = x @ w_seq + b_seq (f64). Also inits rank[].
__global__ __launch_bounds__(256) void k_seqe(const float* __restrict__ x, const float* __restrict__ wsq,
                       const float* __restrict__ bsq, double* __restrict__ seqe, int* __restrict__ rank) {
    int t = blockIdx.x * 256 + threadIdx.x;   // NSEQ*SDIM = 8192
    int k = t >> 4, s = t & 15;
    double acc = (double)bsq[s];
#pragma unroll
    for (int q = 0; q < ALPH; ++q)
        acc += (double)x[k * ALPH + q] * (double)wsq[q * SDIM + s];
    seqe[t] = acc;
    if (t < NPOOL) rank[t] = 1 << 30;
}

// C(4096x64 f64) += A(4096x4096 f32) @ B(4096x64 f64), split-K, VALU f64 FMA.
// v9 = v3's exact geometry (64x64 block, SPLITK16, 4 resident blocks/CU, 4.2M atomics —
// measured 97% of LDS floor) with A kept f32 in LDS (A input IS f32 -> exact math):
// thread (tx=t&15, ty=t>>4) owns rows {4ty..4ty+3}, cols {2tx,2tx+1,2tx+32,2tx+33}.
// Per kk: 1 float4 A-read (quarter-wave broadcast, free) + 2 double2 B-reads (2-way, free)
// = 3 LDS reads per 16 MACs (v3 was 4) -> floor 84.7*96/128 ~ 64us.
// A-write swizzle slot = r ^ (kq<<2): 16 distinct banks/quarter-wave (v8-verified);
// element (k,row) lives at slot row^(4*(k>>3)); read base 4*(ty^(kk>>3)) stays contiguous.
__global__ __launch_bounds__(256, 4) void gemm_f64_v9(const float* __restrict__ A, const double* __restrict__ B,
                                                      double* __restrict__ C) {
    __shared__ float  As[32][68];   // [k][row-slot swizzled], f32 (8.7 KB)
    __shared__ double Bs[32][66];   // [k][col] (16.9 KB)
    int t  = threadIdx.x;
    int tx = t & 15;
    int ty = t >> 4;
    int row0 = blockIdx.x * 64;
    int k0   = blockIdx.y * KSLICE;
    int kq = t & 3, kb = kq << 3;    // staging: this thread covers k = kb..kb+7
    int ar = t >> 2;                 // staging A row (0..63)

    double acc[4][4] = {};

    for (int kt = k0; kt < k0 + KSLICE; kt += 32) {
        // stage A: 64 rows x 32 k, f32, swizzled slots
        {
            const float* Ap = A + (size_t)(row0 + ar) * NPOOL + kt + kq * 8;
            float4 f0 = *(const float4*)Ap;
            float4 f1 = *(const float4*)(Ap + 4);
            int rs = ar ^ (kq << 2);
            As[kb + 0][rs] = f0.x; As[kb + 1][rs] = f0.y;
            As[kb + 2][rs] = f0.z; As[kb + 3][rs] = f0.w;
            As[kb + 4][rs] = f1.x; As[kb + 5][rs] = f1.y;
            As[kb + 6][rs] = f1.z; As[kb + 7][rs] = f1.w;
        }
        // stage B: 32 k-rows x 64 cols (double2)
#pragma unroll
        for (int it = 0; it < 4; ++it) {
            int e = 2 * t + 512 * it;
            *(double2*)&Bs[e >> 6][e & 63] = *(const double2*)&B[(size_t)(kt + (e >> 6)) * 64 + (e & 63)];
        }
        __syncthreads();
#pragma unroll
        for (int kk = 0; kk < 32; ++kk) {
            int abase = 4 * (ty ^ (kk >> 3));           // compile-time kk>>3 (unrolled)
            float4 af = *(const float4*)&As[kk][abase];
            double a[4] = {(double)af.x, (double)af.y, (double)af.z, (double)af.w};
            double2 b01 = *(const double2*)&Bs[kk][2 * tx];
            double2 b23 = *(const double2*)&Bs[kk][2 * tx + 32];
            double b[4] = {b01.x, b01.y, b23.x, b23.y};
#pragma unroll
            for (int i = 0; i < 4; ++i)
#pragma unroll
                for (int j = 0; j < 4; ++j)
                    acc[i][j] = fma(a[i], b[j], acc[i][j]);
        }
        __syncthreads();
    }

    int cc[4] = {2 * tx, 2 * tx + 1, 2 * tx + 32, 2 * tx + 33};
#pragma unroll
    for (int i = 0; i < 4; ++i)
#pragma unroll
        for (int j = 0; j < 4; ++j)
            unsafeAtomicAdd(&C[(size_t)(row0 + 4 * ty + i) * 64 + cc[j]], acc[i][j]);
}

// s[i] = relu(T3[i,:] @ w_gcn1) . w_edge[0:64]   (one wave per row; w1 cached in LDS)
__global__ __launch_bounds__(256) void k_head(const double* __restrict__ T3, const float* __restrict__ w1,
                       const float* __restrict__ we, double* __restrict__ s) {
    __shared__ float w1s[64 * 64];
    int tt = threadIdx.x;
    for (int i = tt; i < 64 * 64; i += 256) w1s[i] = w1[i];
    __syncthreads();
    int row = (blockIdx.x * 256 + tt) >> 6;
    int e = tt & 63;
    const double* r = T3 + (size_t)row * 64;
    double h = 0.0;
#pragma unroll
    for (int c = 0; c < 64; ++c)
        h += r[c] * (double)w1s[c * 64 + e];
    double p = (h > 0.0 ? h : 0.0) * (double)we[e];
    for (int off = 32; off; off >>= 1) p += __shfl_down(p, off, 64);
    if (e == 0) s[row] = p;
}

// Full sort of 4096 keys (desc, idx asc on ties) via packed-u64 register bitonic.
__global__ __launch_bounds__(1024) void k_sort3(const double* __restrict__ s, int* __restrict__ order,
                        double* __restrict__ skey, int* __restrict__ orderB) {
    __shared__ unsigned long long P[NPOOL];   // 32 KB
    __shared__ int idxF[NPOOL];               // 16 KB (fallback only)
    __shared__ int fbS;
    int t = threadIdx.x;
    if (t == 0) fbS = 0;
    unsigned long long v[4];
#pragma unroll
    for (int i = 0; i < 4; ++i) {
        int e = 4 * t + i;
        unsigned long long srt = sortable_u64(s[e]);
        v[i] = ((~(srt >> 12)) << 12) | (unsigned long long)e;
    }

#define SHFL_ROUND(jj, kk)                                                        \
    {                                                                             \
        int lm = (int)((jj) >> 2);                                                \
        _Pragma("unroll")                                                         \
        for (int i = 0; i < 4; ++i) {                                             \
            unsigned long long p = (unsigned long long)__shfl_xor((long long)v[i], lm, 64); \
            unsigned e = 4u * (unsigned)t + (unsigned)i;                          \
            bool takeMin = (((e & (jj)) == 0u) == ((e & (kk)) == 0u));            \
            unsigned long long mn = v[i] < p ? v[i] : p;                          \
            unsigned long long mx = v[i] < p ? p : v[i];                          \
            v[i] = takeMin ? mn : mx;                                             \
        }                                                                         \
    }

#define LOCAL_ROUNDS(kk)                                                          \
    {                                                                             \
        if ((kk) >= 4) {                                                          \
            _Pragma("unroll")                                                     \
            for (int i = 0; i < 2; ++i) {                                         \
                unsigned e = 4u * (unsigned)t + (unsigned)i;                      \
                bool asc = ((e & (kk)) == 0u);                                    \
                unsigned long long a = v[i], b = v[i + 2];                        \
                bool sw = asc ? (a > b) : (a < b);                                \
                v[i] = sw ? b : a; v[i + 2] = sw ? a : b;                         \
            }                                                                     \
        }                                                                         \
        _Pragma("unroll")                                                         \
        for (int i = 0; i < 4; i += 2) {                                          \
            unsigned e = 4u * (unsigned)t + (unsigned)i;                          \
            bool asc = ((e & (kk)) == 0u);                                        \
            unsigned long long a = v[i], b = v[i + 1];                            \
            bool sw = asc ? (a > b) : (a < b);                                    \
            v[i] = sw ? b : a; v[i + 1] = sw ? a : b;                             \
        }                                                                         \
    }

    // phase 1: k = 2..256 (purely intra-wave)
    for (unsigned k = 2; k <= 256; k <<= 1) {
        for (unsigned j = k >> 1; j >= 4; j >>= 1) SHFL_ROUND(j, k)
        LOCAL_ROUNDS(k)
    }
    // phase 2: k = 512..4096 (j>=256 via LDS, rest intra-wave)
    for (unsigned k = 512; k <= 4096; k <<= 1) {
        for (unsigned j = k >> 1; j >= 256; j >>= 1) {
            __syncthreads();
            P[4 * t + 0] = v[0]; P[4 * t + 1] = v[1];
            P[4 * t + 2] = v[2]; P[4 * t + 3] = v[3];
            __syncthreads();
            unsigned base = (4u * (unsigned)t) ^ j;
#pragma unroll
            for (int i = 0; i < 4; ++i) {
                unsigned e = 4u * (unsigned)t + (unsigned)i;
                unsigned long long p = P[base + i];
                bool takeMin = (((e & j) == 0u) == ((e & k) == 0u));
                unsigned long long mn = v[i] < p ? v[i] : p;
                unsigned long long mx = v[i] < p ? p : v[i];
                v[i] = takeMin ? mn : mx;
            }
        }
        for (unsigned j = 128; j >= 4; j >>= 1) SHFL_ROUND(j, k)
        LOCAL_ROUNDS(k)
    }
#undef SHFL_ROUND
#undef LOCAL_ROUNDS

    __syncthreads();
    P[4 * t + 0] = v[0]; P[4 * t + 1] = v[1];
    P[4 * t + 2] = v[2]; P[4 * t + 3] = v[3];
    __syncthreads();
    // truncation-tie guard over positions 0..512 (adjacent pairs)
    if (t < 512) {
        unsigned long long pa = P[t], pb = P[t + 1];
        if ((pa >> 12) == (pb >> 12)) {
            int ia = (int)(pa & 4095ULL), ib = (int)(pb & 4095ULL);
            if (sortable_u64(s[ia]) != sortable_u64(s[ib])) atomicOr(&fbS, 1);
        }
    }
    __syncthreads();
    if (fbS == 0) {
        if (t < NSEQ) {
            int id = (int)(P[t] & 4095ULL);
            order[t] = id; skey[t] = s[id]; orderB[t] = (int)(P[0] & 4095ULL);
        }
        return;
    }
    // exact fallback: full bitonic on (sortable64, idx)
    for (int i = t; i < NPOOL; i += 1024) { P[i] = sortable_u64(s[i]); idxF[i] = i; }
    __syncthreads();
    for (int k2 = 2; k2 <= NPOOL; k2 <<= 1) {
        for (int j = k2 >> 1; j > 0; j >>= 1) {
            for (int tt = t; tt < NPOOL; tt += 1024) {
                int l = tt ^ j;
                if (l > tt) {
                    unsigned long long ka = P[tt], kb = P[l];
                    int ia = idxF[tt], ib = idxF[l];
                    bool aBefore = (ka > kb) || (ka == kb && ia < ib);
                    bool asc = ((tt & k2) == 0);
                    if (asc ? !aBefore : aBefore) { P[tt] = kb; P[l] = ka; idxF[tt] = ib; idxF[l] = ia; }
                }
            }
            __syncthreads();
        }
    }
    for (int tt = t; tt < NSEQ; tt += 1024) {
        int id = idxF[tt];
        order[tt] = id; skey[tt] = s[id]; orderB[tt] = idxF[0];
    }
}

// per-k recurrence pieces for BOTH hypotheses (which = blockIdx.x>>9): A uses orderA, B uses orderB
__global__ __launch_bounds__(256) void k_perk2(const double* __restrict__ Fin, const int* __restrict__ orderA,
                       const int* __restrict__ orderBv,
                       const float* __restrict__ w2, const float* __restrict__ wgr, const float* __restrict__ bgr,
                       const float* __restrict__ wga, const float* __restrict__ bga,
                       double* __restrict__ phi_inf, double* __restrict__ phi_pair, double* __restrict__ hlast) {
    const double r2 = 0.70710678118654752440;
    const double r3 = 0.57735026918962576451;
    __shared__ double u[4][64];
    __shared__ double comb[3][64];
    __shared__ double v[3][64];
    __shared__ double hgg[3][2][GDIM];
    int which = blockIdx.x >> 9;
    int k = blockIdx.x & (NSEQ - 1);
    const int* order = which ? orderBv : orderA;
    double* pi = phi_inf  + (size_t)which * NSEQ * GDIM;
    double* pp = phi_pair + (size_t)which * NSEQ * GDIM;
    double* hl = hlast    + (size_t)which * NSEQ * 64;
    int t = threadIdx.x;
    {
        int w = t >> 6, e = t & 63;
        int j = k - 3 + w;
        u[w][e] = (j >= 0) ? Fin[(size_t)order[j] * 64 + e] : 0.0;
    }
    __syncthreads();
    if (t < 192) {
        int w = t >> 6, e = t & 63;
        double dh_km3 = (k - 3 == 0) ? r2 : r3;
        double dh_km2 = (k - 2 == 0) ? r2 : r3;
        double dh_km1 = (k - 1 == 0) ? r2 : r3;
        double outer, c0, c1, c2, c3;
        if (w == 0) {        // v_{k-2} (final form)
            outer = dh_km2; c0 = dh_km3; c1 = dh_km2; c2 = dh_km1; c3 = 0.0;
        } else if (w == 1) { // v_{k-1}^{(k)}
            outer = dh_km1; c0 = 0.0; c1 = dh_km2; c2 = dh_km1; c3 = r2;
        } else {             // v_k^{(k)}
            if (k == 0) { outer = 1.0; c0 = c1 = c2 = 0.0; c3 = 1.0; }
            else        { outer = r2;  c0 = c1 = 0.0; c2 = dh_km1; c3 = r2; }
        }
        comb[w][e] = outer * (c0 * u[0][e] + c1 * u[1][e] + c2 * u[2][e] + c3 * u[3][e]);
    }
    __syncthreads();
    if (t < 192) {
        int w = t >> 6, e = t & 63;
        double acc = 0.0;
#pragma unroll
        for (int j = 0; j < 64; ++j)
            acc += comb[w][j] * (double)w2[j * 64 + e];
        v[w][e] = acc;
    }
    __syncthreads();
    for (int rep = 0; rep < 3; ++rep) {
        int d = t & 127, g = t >> 7;
        const float* W = g ? wga : wgr;
        const float* B = g ? bga : bgr;
        double acc = (double)B[d];
#pragma unroll
        for (int j = 0; j < 64; ++j)
            acc += v[rep][j] * (double)W[j * GDIM + d];
        hgg[rep][g][d] = acc;
    }
    __syncthreads();
    if (t < 128) {
        if (k >= 2) pi[(size_t)(k - 2) * GDIM + t] = hgg[0][0][t] * sigm_d(hgg[0][1][t]);
        double ppv = hgg[2][0][t] * sigm_d(hgg[2][1][t]);
        if (k >= 1) ppv += hgg[1][0][t] * sigm_d(hgg[1][1][t]);
        pp[(size_t)k * GDIM + t] = ppv;
    } else if (t < 192) {
        hl[(size_t)k * 64 + (t - 128)] = v[2][t - 128];
    }
}

// per-dim prefix scan for both hypotheses: hgr[k] = sum_{j<=k-2} phi_inf[j] + phi_pair[k]
__global__ __launch_bounds__(512) void k_scan2(const double* __restrict__ phi_inf, const double* __restrict__ phi_pair,
                       double* __restrict__ hgr) {
    __shared__ double sb[NSEQ];
    int which = blockIdx.x >> 7;
    int d = blockIdx.x & (GDIM - 1), t = threadIdx.x;
    const double* pi = phi_inf  + (size_t)which * NSEQ * GDIM;
    const double* pp = phi_pair + (size_t)which * NSEQ * GDIM;
    double* hg = hgr + (size_t)which * NSEQ * GDIM;
    sb[t] = (t >= 2) ? pi[(size_t)(t - 2) * GDIM + d] : 0.0;
    for (int off = 1; off < NSEQ; off <<= 1) {
        __syncthreads();
        double add = (t >= off) ? sb[t - off] : 0.0;
        __syncthreads();
        sb[t] += add;
    }
    __syncthreads();
    hg[(size_t)t * GDIM + d] = sb[t] + pp[(size_t)t * GDIM + d];
}

// c_k for both hypotheses; one wave per (which, k)
__global__ __launch_bounds__(64) void k_c2(const double* __restrict__ hlast, const double* __restrict__ hgr,
                   const double* __restrict__ seqe, const float* __restrict__ we,
                   double* __restrict__ cA, double* __restrict__ cB) {
    int which = blockIdx.x >> 9;
    int k = blockIdx.x & (NSEQ - 1), j = threadIdx.x;
    const double* hl = hlast + (size_t)which * NSEQ * 64;
    const double* hg = hgr   + (size_t)which * NSEQ * GDIM;
    double* c = which ? cB : cA;
    double ts = 0.0;
    if (k > 0) {
        ts += relu_d(hl[(size_t)(k - 1) * 64 + j]) * (double)we[64 + j];
        ts += relu_d(hg[(size_t)(k - 1) * GDIM + j]) * (double)we[144 + j];
        ts += relu_d(hg[(size_t)(k - 1) * GDIM + 64 + j]) * (double)we[208 + j];
    }
    if (j < 16) ts += relu_d(seqe[(size_t)k * SDIM + j]) * (double)we[128 + j];
    for (int off = 32; off; off >>= 1) ts += __shfl_down(ts, off, 64);
    if (j == 0) c[k] = ts;
}

// block 0: regime A valid iff skey[t]+cA[t] > 0 for all t>=1
// block 1: regime B valid iff skey[1]+cB[k] <= 0 for all k>=1
__global__ __launch_bounds__(512) void k_verify2(const double* __restrict__ skey, const double* __restrict__ cA,
                         const double* __restrict__ cB, int* __restrict__ flagA, int* __restrict__ flagB) {
    __shared__ int bad;
    int t = threadIdx.x;
    if (t == 0) bad = 0;
    __syncthreads();
    if (blockIdx.x == 0) {
        if (t >= 1 && !(skey[t] + cA[t] > 0.0)) atomicOr(&bad, 1);
        __syncthreads();
        if (t == 0) flagA[0] = bad;
    } else {
        if (t >= 1 && (skey[1] + cB[t] > 0.0)) atomicOr(&bad, 1);
        __syncthreads();
        if (t == 0) flagB[0] = bad;
    }
}

// pick regime: mode 0 = advance (A), 1 = repeat (B), 2 = fallback
__global__ __launch_bounds__(512) void k_select(const int* __restrict__ flagA, const int* __restrict__ flagB,
                        const double* __restrict__ cA, const double* __restrict__ cB,
                        const int* __restrict__ order, double* __restrict__ c,
                        int* __restrict__ idxs_sel, int* __restrict__ mode) {
    int t = threadIdx.x;
    if (flagA[0] == 0) {
        c[t] = cA[t]; idxs_sel[t] = order[t];
        if (t == 0) mode[0] = 0;
    } else if (flagB[0] == 0) {
        c[t] = cB[t]; idxs_sel[t] = order[0];
        if (t == 0) mode[0] = 1;
    } else {
        if (t == 0) mode[0] = 2;
    }
}

// exact sequential fallback (runs only when both fast paths invalid)
__global__ __launch_bounds__(256) void k_fallback(const int* __restrict__ mode,
        const double* __restrict__ Fin, const int* __restrict__ order, const double* __restrict__ skey,
        const double* __restrict__ seqe,
        const float* __restrict__ w2, const float* __restrict__ wgr, const float* __restrict__ bgr,
        const float* __restrict__ wga, const float* __restrict__ bga, const float* __restrict__ we,
        int* __restrict__ idxs_sel, double* __restrict__ c) {
    if (mode[0] != 2) return;
    const double r2 = 0.70710678118654752440;
    const double r3 = 0.57735026918962576451;
    __shared__ double u[4][64];
    __shared__ double comb[3][64];
    __shared__ double v[3][64];
    __shared__ double hgg[3][2][GDIM];
    __shared__ double Phi[GDIM], hgraph[GDIM], hlastS[64];
    __shared__ int selS, ptrS, minS_;
    int t = threadIdx.x;
    if (t < 64) { u[0][t] = u[1][t] = u[2][t] = u[3][t] = 0.0; hlastS[t] = 0.0; }
    if (t < 128) { Phi[t] = 0.0; hgraph[t] = 0.0; }
    if (t == 0) { ptrS = 0; minS_ = 0x7fffffff; }
    __syncthreads();
    for (int k = 0; k < NSEQ; ++k) {
        if (t < 64) {
            int j = t;
            double ts = relu_d(hlastS[j]) * (double)we[64 + j]
                      + relu_d(hgraph[j]) * (double)we[144 + j]
                      + relu_d(hgraph[64 + j]) * (double)we[208 + j];
            if (j < 16) ts += relu_d(seqe[(size_t)k * SDIM + j]) * (double)we[128 + j];
            for (int off = 32; off; off >>= 1) ts += __shfl_down(ts, off, 64);
            if (j == 0) {
                c[k] = ts;
                int ptr = ptrS, idx;
                if (ptr == 0) { idx = order[0]; minS_ = idx; ptrS = 1; }
                else if (skey[ptr] + ts > 0.0) {
                    idx = order[ptr];
                    if (idx < minS_) minS_ = idx;
                    ptrS = ptr + 1;
                } else idx = minS_;
                selS = idx;
                idxs_sel[k] = idx;
            }
        }
        __syncthreads();
        int idx = selS;
        if (t < 64) u[k & 3][t] = Fin[(size_t)idx * 64 + t];
        __syncthreads();
        if (t < 192) {
            int w = t >> 6, e = t & 63;
            double dh_km3 = (k - 3 == 0) ? r2 : r3;
            double dh_km2 = (k - 2 == 0) ? r2 : r3;
            double dh_km1 = (k - 1 == 0) ? r2 : r3;
            double outer, c0, c1, c2, c3;
            if (w == 0) {
                outer = dh_km2; c0 = dh_km3; c1 = dh_km2; c2 = dh_km1; c3 = 0.0;
            } else if (w == 1) {
                outer = dh_km1; c0 = 0.0; c1 = dh_km2; c2 = dh_km1; c3 = r2;
            } else {
                if (k == 0) { outer = 1.0; c0 = c1 = c2 = 0.0; c3 = 1.0; }
                else        { outer = r2;  c0 = c1 = 0.0; c2 = dh_km1; c3 = r2; }
            }
            double uu0 = u[(k - 3) & 3][e], uu1 = u[(k - 2) & 3][e], uu2 = u[(k - 1) & 3][e], uu3 = u[k & 3][e];
            comb[w][e] = outer * (c0 * uu0 + c1 * uu1 + c2 * uu2 + c3 * uu3);
        }
        __syncthreads();
        if (t < 192) {
            int w = t >> 6, e = t & 63;
            double acc = 0.0;
#pragma unroll
            for (int j = 0; j < 64; ++j)
                acc += comb[w][j] * (double)w2[j * 64 + e];
            v[w][e] = acc;
        }
        __syncthreads();
        for (int rep = 0; rep < 3; ++rep) {
            int d = t & 127, g = t >> 7;
            const float* W = g ? wga : wgr;
            const float* B = g ? bga : bgr;
            double acc = (double)B[d];
#pragma unroll
            for (int j = 0; j < 64; ++j)
                acc += v[rep][j] * (double)W[j * GDIM + d];
            hgg[rep][g][d] = acc;
        }
        __syncthreads();
        if (t < 128) {
            if (k >= 2) Phi[t] += hgg[0][0][t] * sigm_d(hgg[0][1][t]);
            double hg = Phi[t] + hgg[2][0][t] * sigm_d(hgg[2][1][t]);
            if (k >= 1) hg += hgg[1][0][t] * sigm_d(hgg[1][1][t]);
            hgraph[t] = hg;
        } else if (t < 192) {
            hlastS[t - 128] = v[2][t - 128];
        }
        __syncthreads();
    }
}

__global__ __launch_bounds__(256) void k_rank_set(const int* __restrict__ idxs_sel, int* __restrict__ rank,
                           float* __restrict__ out) {
    int t = blockIdx.x * 256 + threadIdx.x;
    if (t < NSEQ) {
        atomicMin(&rank[idxs_sel[t]], t);
        out[(size_t)NSEQ * NPOOL + t] = (float)idxs_sel[t];
    }
}

__global__ __launch_bounds__(256) void k_fill(const double* __restrict__ s, const double* __restrict__ c,
                       const int* __restrict__ rank, const float* __restrict__ be, float* __restrict__ out) {
    size_t t = (size_t)blockIdx.x * 256 + threadIdx.x;   // NSEQ*NPOOL
    int k = (int)(t >> 12);
    int i = (int)(t & 4095);
    double bed = (double)be[0];
    bool masked = rank[i] < k;
    out[t] = masked ? (float)bed : (float)(s[i] + c[k] + bed);
}

extern "C" void kernel_launch(void* const* d_in, const int* in_sizes, int n_in,
                              void* d_out, int out_size, void* d_ws, size_t ws_size,
                              hipStream_t stream) {
    const float* x    = (const float*)d_in[0];
    const float* f    = (const float*)d_in[1];
    const float* amat = (const float*)d_in[2];
    const float* dmat = (const float*)d_in[3];
    const float* wf   = (const float*)d_in[4];
    const float* bf   = (const float*)d_in[5];
    const float* w1   = (const float*)d_in[6];
    const float* w2   = (const float*)d_in[7];
    const float* wgr  = (const float*)d_in[8];
    const float* bgr  = (const float*)d_in[9];
    const float* wga  = (const float*)d_in[10];
    const float* bga  = (const float*)d_in[11];
    const float* we   = (const float*)d_in[12];
    const float* be   = (const float*)d_in[13];
    const float* wsq  = (const float*)d_in[14];
    const float* bsq  = (const float*)d_in[15];
    float* out = (float*)d_out;

    char* p = (char*)d_ws;
    const size_t BIG = (size_t)NPOOL * 64 * sizeof(double);   // 2 MB
    double* R    = (double*)p; p += BIG;
    double* Fin  = (double*)p; p += BIG;
    double* T1   = (double*)p; p += BIG;
    double* T2   = (double*)p; p += BIG;
    double* T3   = (double*)p; p += BIG;
    double* seqe = (double*)p; p += (size_t)NSEQ * SDIM * sizeof(double);
    double* s    = (double*)p; p += (size_t)NPOOL * sizeof(double);
    double* skey = (double*)p; p += (size_t)NSEQ * sizeof(double);
    double* phi_inf  = (double*)p; p += 2 * (size_t)NSEQ * GDIM * sizeof(double);
    double* phi_pair = (double*)p; p += 2 * (size_t)NSEQ * GDIM * sizeof(double);
    double* hgr   = (double*)p; p += 2 * (size_t)NSEQ * GDIM * sizeof(double);
    double* hlast = (double*)p; p += 2 * (size_t)NSEQ * 64 * sizeof(double);
    double* cA    = (double*)p; p += (size_t)NSEQ * sizeof(double);
    double* cB    = (double*)p; p += (size_t)NSEQ * sizeof(double);
    double* c     = (double*)p; p += (size_t)NSEQ * sizeof(double);
    int* order    = (int*)p; p += 2048;
    int* orderB   = (int*)p; p += 2048;
    int* idxs_sel = (int*)p; p += 2048;
    int* rank     = (int*)p; p += (size_t)NPOOL * sizeof(int);
    int* flagA    = (int*)p; p += 256;
    int* flagB    = (int*)p; p += 256;
    int* mode     = (int*)p; p += 256;

    dim3 ggrid(NPOOL / 64, SPLITK);   // 64 x 16 = 1024 blocks

    k_prep<<<1024, 256, 0, stream>>>(f, wf, bf, Fin, R, T1, T2, T3);  // also zeroes T1,T2,T3
    k_seqe<<<32, 256, 0, stream>>>(x, wsq, bsq, seqe, rank);          // also inits rank

    gemm_f64_v9<<<ggrid, 256, 0, stream>>>(dmat, R, T1);    // t1 = d @ R
    gemm_f64_v9<<<ggrid, 256, 0, stream>>>(amat, T1, T2);   // t2 = a @ t1
    gemm_f64_v9<<<ggrid, 256, 0, stream>>>(dmat, T2, T3);   // t3 = d @ t2

    k_head<<<NPOOL / 4, 256, 0, stream>>>(T3, w1, we, s);
    k_sort3<<<1, 1024, 0, stream>>>(s, order, skey, orderB);

    // both hypotheses fused (A: sorted order; B: repeat order[0])
    k_perk2<<<2 * NSEQ, 256, 0, stream>>>(Fin, order, orderB, w2, wgr, bgr, wga, bga, phi_inf, phi_pair, hlast);
    k_scan2<<<2 * GDIM, 512, 0, stream>>>(phi_inf, phi_pair, hgr);
    k_c2<<<2 * NSEQ, 64, 0, stream>>>(hlast, hgr, seqe, we, cA, cB);
    k_verify2<<<2, 512, 0, stream>>>(skey, cA, cB, flagA, flagB);

    k_select<<<1, 512, 0, stream>>>(flagA, flagB, cA, cB, order, c, idxs_sel, mode);
    k_fallback<<<1, 256, 0, stream>>>(mode, Fin, order, skey, seqe, w2, wgr, bgr, wga, bga, we, idxs_sel, c);

    k_rank_set<<<2, 256, 0, stream>>>(idxs_sel, rank, out);
    k_fill<<<(NSEQ * NPOOL) / 256, 256, 0, stream>>>(s, c, rank, be, out);
}

// Round 10
// 464.850 us; speedup vs baseline: 4.5561x; 1.0098x over previous
//
#include <hip/hip_runtime.h>
#include <math.h>

#define NPOOL 4096
#define NSEQ  512
#define NF    20
#define EDIM  64
#define GDIM  128
#define SDIM  16
#define ALPH  20
#define SPLITK 16
#define KSLICE (NPOOL / SPLITK)   // 256
#define KSTEPS (KSLICE / 32)      // 8

__device__ __forceinline__ double relu_d(double x){ return x > 0.0 ? x : 0.0; }
__device__ __forceinline__ double sigm_d(double x){ return 1.0 / (1.0 + exp(-x)); }

__device__ __forceinline__ unsigned long long sortable_u64(double x) {
    x = x + 0.0;                                  // canonicalize -0 -> +0
    unsigned long long b = (unsigned long long)__double_as_longlong(x);
    return b ^ ((b >> 63) ? ~0ULL : 0x8000000000000000ULL);
}

// Fin[i][e] = f @ w_feat + b_feat (f64); R = relu(Fin). Also zeroes T1,T2,T3.
__global__ __launch_bounds__(256) void k_prep(const float* __restrict__ f, const float* __restrict__ wf,
                       const float* __restrict__ bf, double* __restrict__ Fin, double* __restrict__ R,
                       double* __restrict__ T1z, double* __restrict__ T2z, double* __restrict__ T3z) {
    int t = blockIdx.x * 256 + threadIdx.x;   // NPOOL*EDIM
    int i = t >> 6, e = t & 63;
    double acc = (double)bf[e];
#pragma unroll
    for (int j = 0; j < NF; ++j)
        acc += (double)f[i * NF + j] * (double)wf[j * EDIM + e];
    Fin[t] = acc;
    R[t] = acc > 0.0 ? acc : 0.0;
    T1z[t] = 0.0; T2z[t] = 0.0; T3z[t] = 0.0;
}

// seq_embed = x @ w_seq + b_seq (f64). Also inits rank[].
__global__ __launch_bounds__(256) void k_seqe(const float* __restrict__ x, const float* __restrict__ wsq,
                       const float* __restrict__ bsq, double* __restrict__ seqe, int* __restrict__ rank) {
    int t = blockIdx.x * 256 + threadIdx.x;   // NSEQ*SDIM = 8192
    int k = t >> 4, s = t & 15;
    double acc = (double)bsq[s];
#pragma unroll
    for (int q = 0; q < ALPH; ++q)
        acc += (double)x[k * ALPH + q] * (double)wsq[q * SDIM + s];
    seqe[t] = acc;
    if (t < NPOOL) rank[t] = 1 << 30;
}

// C(4096x64 f64) += A(4096x4096 f32) @ B(4096x64 f64), split-K, VALU f64 FMA.
// v10 = v9 (80.6us, 97%-verified layout) + register-prefetch pipeline:
// prefetch tile k+1 into 24 VGPRs (8 f32 + 8 f64) BEFORE the compute loop; the
// compiler's s_waitcnt for those loads lands just before the post-barrier LDS store,
// hiding ~900cyc HBM latency under 512 FMAs. v7's spill failure was the 64-VGPR acc
// + runtime branch; v9's acc is 32 VGPRs (44 total) -> ~90 VGPRs, no spill at 4 blocks/CU.
// Loop structure: step<KSTEPS-1 prefetch (always-valid addresses), final compute peeled.
__global__ __launch_bounds__(256, 4) void gemm_f64_v10(const float* __restrict__ A, const double* __restrict__ B,
                                                       double* __restrict__ C) {
    __shared__ float  As[32][68];   // [k][row-slot swizzled], f32 (8.7 KB)
    __shared__ double Bs[32][66];   // [k][col] (16.9 KB)
    int t  = threadIdx.x;
    int tx = t & 15;
    int ty = t >> 4;
    int row0 = blockIdx.x * 64;
    int k0   = blockIdx.y * KSLICE;
    int kq = t & 3, kb = kq << 3;    // staging: this thread covers k = kb..kb+7
    int ar = t >> 2;                 // staging A row (0..63)
    int rs = ar ^ (kq << 2);         // swizzled slot (v8/v9-verified)
    int e0 = 2 * t, e1 = e0 + 512, e2 = e0 + 1024, e3 = e0 + 1536;

    const float* Abase = A + (size_t)(row0 + ar) * NPOOL + kq * 8;

    double acc[4][4] = {};
    float4  a0, a1;
    double2 b0, b1, b2, b3;

#define LOADG(KT)                                                                 \
    {                                                                             \
        a0 = *(const float4*)(Abase + (KT));                                      \
        a1 = *(const float4*)(Abase + (KT) + 4);                                  \
        b0 = *(const double2*)&B[(size_t)((KT) + (e0 >> 6)) * 64 + (e0 & 63)];    \
        b1 = *(const double2*)&B[(size_t)((KT) + (e1 >> 6)) * 64 + (e1 & 63)];    \
        b2 = *(const double2*)&B[(size_t)((KT) + (e2 >> 6)) * 64 + (e2 & 63)];    \
        b3 = *(const double2*)&B[(size_t)((KT) + (e3 >> 6)) * 64 + (e3 & 63)];    \
    }

#define STORELDS()                                                                \
    {                                                                             \
        As[kb + 0][rs] = a0.x; As[kb + 1][rs] = a0.y;                             \
        As[kb + 2][rs] = a0.z; As[kb + 3][rs] = a0.w;                             \
        As[kb + 4][rs] = a1.x; As[kb + 5][rs] = a1.y;                             \
        As[kb + 6][rs] = a1.z; As[kb + 7][rs] = a1.w;                             \
        *(double2*)&Bs[e0 >> 6][e0 & 63] = b0;                                    \
        *(double2*)&Bs[e1 >> 6][e1 & 63] = b1;                                    \
        *(double2*)&Bs[e2 >> 6][e2 & 63] = b2;                                    \
        *(double2*)&Bs[e3 >> 6][e3 & 63] = b3;                                    \
    }

#define COMPUTE32()                                                               \
    {                                                                             \
        _Pragma("unroll")                                                         \
        for (int kk = 0; kk < 32; ++kk) {                                         \
            int abase = 4 * (ty ^ (kk >> 3));                                     \
            float4 af = *(const float4*)&As[kk][abase];                           \
            double a[4] = {(double)af.x, (double)af.y, (double)af.z, (double)af.w}; \
            double2 q01 = *(const double2*)&Bs[kk][2 * tx];                       \
            double2 q23 = *(const double2*)&Bs[kk][2 * tx + 32];                  \
            double b[4] = {q01.x, q01.y, q23.x, q23.y};                           \
            _Pragma("unroll")                                                     \
            for (int i = 0; i < 4; ++i)                                           \
                _Pragma("unroll")                                                 \
                for (int j = 0; j < 4; ++j)                                       \
                    acc[i][j] = fma(a[i], b[j], acc[i][j]);                       \
        }                                                                         \
    }

    LOADG(k0)
    STORELDS()
    __syncthreads();

    for (int step = 0; step < KSTEPS - 1; ++step) {
        int ktn = k0 + 32 * (step + 1);
        LOADG(ktn)          // prefetch next tile (latency hidden under compute)
        COMPUTE32()
        __syncthreads();
        STORELDS()
        __syncthreads();
    }
    COMPUTE32()

#undef LOADG
#undef STORELDS
#undef COMPUTE32

    int cc[4] = {2 * tx, 2 * tx + 1, 2 * tx + 32, 2 * tx + 33};
#pragma unroll
    for (int i = 0; i < 4; ++i)
#pragma unroll
        for (int j = 0; j < 4; ++j)
            unsafeAtomicAdd(&C[(size_t)(row0 + 4 * ty + i) * 64 + cc[j]], acc[i][j]);
}

// s[i] = relu(T3[i,:] @ w_gcn1) . w_edge[0:64]   (one wave per row; w1 cached in LDS)
__global__ __launch_bounds__(256) void k_head(const double* __restrict__ T3, const float* __restrict__ w1,
                       const float* __restrict__ we, double* __restrict__ s) {
    __shared__ float w1s[64 * 64];
    int tt = threadIdx.x;
    for (int i = tt; i < 64 * 64; i += 256) w1s[i] = w1[i];
    __syncthreads();
    int row = (blockIdx.x * 256 + tt) >> 6;
    int e = tt & 63;
    const double* r = T3 + (size_t)row * 64;
    double h = 0.0;
#pragma unroll
    for (int c = 0; c < 64; ++c)
        h += r[c] * (double)w1s[c * 64 + e];
    double p = (h > 0.0 ? h : 0.0) * (double)we[e];
    for (int off = 32; off; off >>= 1) p += __shfl_down(p, off, 64);
    if (e == 0) s[row] = p;
}

// Full sort of 4096 keys (desc, idx asc on ties) via packed-u64 register bitonic.
__global__ __launch_bounds__(1024) void k_sort3(const double* __restrict__ s, int* __restrict__ order,
                        double* __restrict__ skey, int* __restrict__ orderB) {
    __shared__ unsigned long long P[NPOOL];   // 32 KB
    __shared__ int idxF[NPOOL];               // 16 KB (fallback only)
    __shared__ int fbS;
    int t = threadIdx.x;
    if (t == 0) fbS = 0;
    unsigned long long v[4];
#pragma unroll
    for (int i = 0; i < 4; ++i) {
        int e = 4 * t + i;
        unsigned long long srt = sortable_u64(s[e]);
        v[i] = ((~(srt >> 12)) << 12) | (unsigned long long)e;
    }

#define SHFL_ROUND(jj, kk)                                                        \
    {                                                                             \
        int lm = (int)((jj) >> 2);                                                \
        _Pragma("unroll")                                                         \
        for (int i = 0; i < 4; ++i) {                                             \
            unsigned long long p = (unsigned long long)__shfl_xor((long long)v[i], lm, 64); \
            unsigned e = 4u * (unsigned)t + (unsigned)i;                          \
            bool takeMin = (((e & (jj)) == 0u) == ((e & (kk)) == 0u));            \
            unsigned long long mn = v[i] < p ? v[i] : p;                          \
            unsigned long long mx = v[i] < p ? p : v[i];                          \
            v[i] = takeMin ? mn : mx;                                             \
        }                                                                         \
    }

#define LOCAL_ROUNDS(kk)                                                          \
    {                                                                             \
        if ((kk) >= 4) {                                                          \
            _Pragma("unroll")                                                     \
            for (int i = 0; i < 2; ++i) {                                         \
                unsigned e = 4u * (unsigned)t + (unsigned)i;                      \
                bool asc = ((e & (kk)) == 0u);                                    \
                unsigned long long a = v[i], b = v[i + 2];                        \
                bool sw = asc ? (a > b) : (a < b);                                \
                v[i] = sw ? b : a; v[i + 2] = sw ? a : b;                         \
            }                                                                     \
        }                                                                         \
        _Pragma("unroll")                                                         \
        for (int i = 0; i < 4; i += 2) {                                          \
            unsigned e = 4u * (unsigned)t + (unsigned)i;                          \
            bool asc = ((e & (kk)) == 0u);                                        \
            unsigned long long a = v[i], b = v[i + 1];                            \
            bool sw = asc ? (a > b) : (a < b);                                    \
            v[i] = sw ? b : a; v[i + 1] = sw ? a : b;                             \
        }                                                                         \
    }

    // phase 1: k = 2..256 (purely intra-wave)
    for (unsigned k = 2; k <= 256; k <<= 1) {
        for (unsigned j = k >> 1; j >= 4; j >>= 1) SHFL_ROUND(j, k)
        LOCAL_ROUNDS(k)
    }
    // phase 2: k = 512..4096 (j>=256 via LDS, rest intra-wave)
    for (unsigned k = 512; k <= 4096; k <<= 1) {
        for (unsigned j = k >> 1; j >= 256; j >>= 1) {
            __syncthreads();
            P[4 * t + 0] = v[0]; P[4 * t + 1] = v[1];
            P[4 * t + 2] = v[2]; P[4 * t + 3] = v[3];
            __syncthreads();
            unsigned base = (4u * (unsigned)t) ^ j;
#pragma unroll
            for (int i = 0; i < 4; ++i) {
                unsigned e = 4u * (unsigned)t + (unsigned)i;
                unsigned long long p = P[base + i];
                bool takeMin = (((e & j) == 0u) == ((e & k) == 0u));
                unsigned long long mn = v[i] < p ? v[i] : p;
                unsigned long long mx = v[i] < p ? p : v[i];
                v[i] = takeMin ? mn : mx;
            }
        }
        for (unsigned j = 128; j >= 4; j >>= 1) SHFL_ROUND(j, k)
        LOCAL_ROUNDS(k)
    }
#undef SHFL_ROUND
#undef LOCAL_ROUNDS

    __syncthreads();
    P[4 * t + 0] = v[0]; P[4 * t + 1] = v[1];
    P[4 * t + 2] = v[2]; P[4 * t + 3] = v[3];
    __syncthreads();
    // truncation-tie guard over positions 0..512 (adjacent pairs)
    if (t < 512) {
        unsigned long long pa = P[t], pb = P[t + 1];
        if ((pa >> 12) == (pb >> 12)) {
            int ia = (int)(pa & 4095ULL), ib = (int)(pb & 4095ULL);
            if (sortable_u64(s[ia]) != sortable_u64(s[ib])) atomicOr(&fbS, 1);
        }
    }
    __syncthreads();
    if (fbS == 0) {
        if (t < NSEQ) {
            int id = (int)(P[t] & 4095ULL);
            order[t] = id; skey[t] = s[id]; orderB[t] = (int)(P[0] & 4095ULL);
        }
        return;
    }
    // exact fallback: full bitonic on (sortable64, idx)
    for (int i = t; i < NPOOL; i += 1024) { P[i] = sortable_u64(s[i]); idxF[i] = i; }
    __syncthreads();
    for (int k2 = 2; k2 <= NPOOL; k2 <<= 1) {
        for (int j = k2 >> 1; j > 0; j >>= 1) {
            for (int tt = t; tt < NPOOL; tt += 1024) {
                int l = tt ^ j;
                if (l > tt) {
                    unsigned long long ka = P[tt], kb = P[l];
                    int ia = idxF[tt], ib = idxF[l];
                    bool aBefore = (ka > kb) || (ka == kb && ia < ib);
                    bool asc = ((tt & k2) == 0);
                    if (asc ? !aBefore : aBefore) { P[tt] = kb; P[l] = ka; idxF[tt] = ib; idxF[l] = ia; }
                }
            }
            __syncthreads();
        }
    }
    for (int tt = t; tt < NSEQ; tt += 1024) {
        int id = idxF[tt];
        order[tt] = id; skey[tt] = s[id]; orderB[tt] = idxF[0];
    }
}

// per-k recurrence pieces for BOTH hypotheses (which = blockIdx.x>>9): A uses orderA, B uses orderB
__global__ __launch_bounds__(256) void k_perk2(const double* __restrict__ Fin, const int* __restrict__ orderA,
                       const int* __restrict__ orderBv,
                       const float* __restrict__ w2, const float* __restrict__ wgr, const float* __restrict__ bgr,
                       const float* __restrict__ wga, const float* __restrict__ bga,
                       double* __restrict__ phi_inf, double* __restrict__ phi_pair, double* __restrict__ hlast) {
    const double r2 = 0.70710678118654752440;
    const double r3 = 0.57735026918962576451;
    __shared__ double u[4][64];
    __shared__ double comb[3][64];
    __shared__ double v[3][64];
    __shared__ double hgg[3][2][GDIM];
    int which = blockIdx.x >> 9;
    int k = blockIdx.x & (NSEQ - 1);
    const int* order = which ? orderBv : orderA;
    double* pi = phi_inf  + (size_t)which * NSEQ * GDIM;
    double* pp = phi_pair + (size_t)which * NSEQ * GDIM;
    double* hl = hlast    + (size_t)which * NSEQ * 64;
    int t = threadIdx.x;
    {
        int w = t >> 6, e = t & 63;
        int j = k - 3 + w;
        u[w][e] = (j >= 0) ? Fin[(size_t)order[j] * 64 + e] : 0.0;
    }
    __syncthreads();
    if (t < 192) {
        int w = t >> 6, e = t & 63;
        double dh_km3 = (k - 3 == 0) ? r2 : r3;
        double dh_km2 = (k - 2 == 0) ? r2 : r3;
        double dh_km1 = (k - 1 == 0) ? r2 : r3;
        double outer, c0, c1, c2, c3;
        if (w == 0) {        // v_{k-2} (final form)
            outer = dh_km2; c0 = dh_km3; c1 = dh_km2; c2 = dh_km1; c3 = 0.0;
        } else if (w == 1) { // v_{k-1}^{(k)}
            outer = dh_km1; c0 = 0.0; c1 = dh_km2; c2 = dh_km1; c3 = r2;
        } else {             // v_k^{(k)}
            if (k == 0) { outer = 1.0; c0 = c1 = c2 = 0.0; c3 = 1.0; }
            else        { outer = r2;  c0 = c1 = 0.0; c2 = dh_km1; c3 = r2; }
        }
        comb[w][e] = outer * (c0 * u[0][e] + c1 * u[1][e] + c2 * u[2][e] + c3 * u[3][e]);
    }
    __syncthreads();
    if (t < 192) {
        int w = t >> 6, e = t & 63;
        double acc = 0.0;
#pragma unroll
        for (int j = 0; j < 64; ++j)
            acc += comb[w][j] * (double)w2[j * 64 + e];
        v[w][e] = acc;
    }
    __syncthreads();
    for (int rep = 0; rep < 3; ++rep) {
        int d = t & 127, g = t >> 7;
        const float* W = g ? wga : wgr;
        const float* B = g ? bga : bgr;
        double acc = (double)B[d];
#pragma unroll
        for (int j = 0; j < 64; ++j)
            acc += v[rep][j] * (double)W[j * GDIM + d];
        hgg[rep][g][d] = acc;
    }
    __syncthreads();
    if (t < 128) {
        if (k >= 2) pi[(size_t)(k - 2) * GDIM + t] = hgg[0][0][t] * sigm_d(hgg[0][1][t]);
        double ppv = hgg[2][0][t] * sigm_d(hgg[2][1][t]);
        if (k >= 1) ppv += hgg[1][0][t] * sigm_d(hgg[1][1][t]);
        pp[(size_t)k * GDIM + t] = ppv;
    } else if (t < 192) {
        hl[(size_t)k * 64 + (t - 128)] = v[2][t - 128];
    }
}

// per-dim prefix scan for both hypotheses: hgr[k] = sum_{j<=k-2} phi_inf[j] + phi_pair[k]
__global__ __launch_bounds__(512) void k_scan2(const double* __restrict__ phi_inf, const double* __restrict__ phi_pair,
                       double* __restrict__ hgr) {
    __shared__ double sb[NSEQ];
    int which = blockIdx.x >> 7;
    int d = blockIdx.x & (GDIM - 1), t = threadIdx.x;
    const double* pi = phi_inf  + (size_t)which * NSEQ * GDIM;
    const double* pp = phi_pair + (size_t)which * NSEQ * GDIM;
    double* hg = hgr + (size_t)which * NSEQ * GDIM;
    sb[t] = (t >= 2) ? pi[(size_t)(t - 2) * GDIM + d] : 0.0;
    for (int off = 1; off < NSEQ; off <<= 1) {
        __syncthreads();
        double add = (t >= off) ? sb[t - off] : 0.0;
        __syncthreads();
        sb[t] += add;
    }
    __syncthreads();
    hg[(size_t)t * GDIM + d] = sb[t] + pp[(size_t)t * GDIM + d];
}

// c_k for both hypotheses; one wave per (which, k)
__global__ __launch_bounds__(64) void k_c2(const double* __restrict__ hlast, const double* __restrict__ hgr,
                   const double* __restrict__ seqe, const float* __restrict__ we,
                   double* __restrict__ cA, double* __restrict__ cB) {
    int which = blockIdx.x >> 9;
    int k = blockIdx.x & (NSEQ - 1), j = threadIdx.x;
    const double* hl = hlast + (size_t)which * NSEQ * 64;
    const double* hg = hgr   + (size_t)which * NSEQ * GDIM;
    double* c = which ? cB : cA;
    double ts = 0.0;
    if (k > 0) {
        ts += relu_d(hl[(size_t)(k - 1) * 64 + j]) * (double)we[64 + j];
        ts += relu_d(hg[(size_t)(k - 1) * GDIM + j]) * (double)we[144 + j];
        ts += relu_d(hg[(size_t)(k - 1) * GDIM + 64 + j]) * (double)we[208 + j];
    }
    if (j < 16) ts += relu_d(seqe[(size_t)k * SDIM + j]) * (double)we[128 + j];
    for (int off = 32; off; off >>= 1) ts += __shfl_down(ts, off, 64);
    if (j == 0) c[k] = ts;
}

// block 0: regime A valid iff skey[t]+cA[t] > 0 for all t>=1
// block 1: regime B valid iff skey[1]+cB[k] <= 0 for all k>=1
__global__ __launch_bounds__(512) void k_verify2(const double* __restrict__ skey, const double* __restrict__ cA,
                         const double* __restrict__ cB, int* __restrict__ flagA, int* __restrict__ flagB) {
    __shared__ int bad;
    int t = threadIdx.x;
    if (t == 0) bad = 0;
    __syncthreads();
    if (blockIdx.x == 0) {
        if (t >= 1 && !(skey[t] + cA[t] > 0.0)) atomicOr(&bad, 1);
        __syncthreads();
        if (t == 0) flagA[0] = bad;
    } else {
        if (t >= 1 && (skey[1] + cB[t] > 0.0)) atomicOr(&bad, 1);
        __syncthreads();
        if (t == 0) flagB[0] = bad;
    }
}

// pick regime: mode 0 = advance (A), 1 = repeat (B), 2 = fallback
__global__ __launch_bounds__(512) void k_select(const int* __restrict__ flagA, const int* __restrict__ flagB,
                        const double* __restrict__ cA, const double* __restrict__ cB,
                        const int* __restrict__ order, double* __restrict__ c,
                        int* __restrict__ idxs_sel, int* __restrict__ mode) {
    int t = threadIdx.x;
    if (flagA[0] == 0) {
        c[t] = cA[t]; idxs_sel[t] = order[t];
        if (t == 0) mode[0] = 0;
    } else if (flagB[0] == 0) {
        c[t] = cB[t]; idxs_sel[t] = order[0];
        if (t == 0) mode[0] = 1;
    } else {
        if (t == 0) mode[0] = 2;
    }
}

// exact sequential fallback (runs only when both fast paths invalid)
__global__ __launch_bounds__(256) void k_fallback(const int* __restrict__ mode,
        const double* __restrict__ Fin, const int* __restrict__ order, const double* __restrict__ skey,
        const double* __restrict__ seqe,
        const float* __restrict__ w2, const float* __restrict__ wgr, const float* __restrict__ bgr,
        const float* __restrict__ wga, const float* __restrict__ bga, const float* __restrict__ we,
        int* __restrict__ idxs_sel, double* __restrict__ c) {
    if (mode[0] != 2) return;
    const double r2 = 0.70710678118654752440;
    const double r3 = 0.57735026918962576451;
    __shared__ double u[4][64];
    __shared__ double comb[3][64];
    __shared__ double v[3][64];
    __shared__ double hgg[3][2][GDIM];
    __shared__ double Phi[GDIM], hgraph[GDIM], hlastS[64];
    __shared__ int selS, ptrS, minS_;
    int t = threadIdx.x;
    if (t < 64) { u[0][t] = u[1][t] = u[2][t] = u[3][t] = 0.0; hlastS[t] = 0.0; }
    if (t < 128) { Phi[t] = 0.0; hgraph[t] = 0.0; }
    if (t == 0) { ptrS = 0; minS_ = 0x7fffffff; }
    __syncthreads();
    for (int k = 0; k < NSEQ; ++k) {
        if (t < 64) {
            int j = t;
            double ts = relu_d(hlastS[j]) * (double)we[64 + j]
                      + relu_d(hgraph[j]) * (double)we[144 + j]
                      + relu_d(hgraph[64 + j]) * (double)we[208 + j];
            if (j < 16) ts += relu_d(seqe[(size_t)k * SDIM + j]) * (double)we[128 + j];
            for (int off = 32; off; off >>= 1) ts += __shfl_down(ts, off, 64);
            if (j == 0) {
                c[k] = ts;
                int ptr = ptrS, idx;
                if (ptr == 0) { idx = order[0]; minS_ = idx; ptrS = 1; }
                else if (skey[ptr] + ts > 0.0) {
                    idx = order[ptr];
                    if (idx < minS_) minS_ = idx;
                    ptrS = ptr + 1;
                } else idx = minS_;
                selS = idx;
                idxs_sel[k] = idx;
            }
        }
        __syncthreads();
        int idx = selS;
        if (t < 64) u[k & 3][t] = Fin[(size_t)idx * 64 + t];
        __syncthreads();
        if (t < 192) {
            int w = t >> 6, e = t & 63;
            double dh_km3 = (k - 3 == 0) ? r2 : r3;
            double dh_km2 = (k - 2 == 0) ? r2 : r3;
            double dh_km1 = (k - 1 == 0) ? r2 : r3;
            double outer, c0, c1, c2, c3;
            if (w == 0) {
                outer = dh_km2; c0 = dh_km3; c1 = dh_km2; c2 = dh_km1; c3 = 0.0;
            } else if (w == 1) {
                outer = dh_km1; c0 = 0.0; c1 = dh_km2; c2 = dh_km1; c3 = r2;
            } else {
                if (k == 0) { outer = 1.0; c0 = c1 = c2 = 0.0; c3 = 1.0; }
                else        { outer = r2;  c0 = c1 = 0.0; c2 = dh_km1; c3 = r2; }
            }
            double uu0 = u[(k - 3) & 3][e], uu1 = u[(k - 2) & 3][e], uu2 = u[(k - 1) & 3][e], uu3 = u[k & 3][e];
            comb[w][e] = outer * (c0 * uu0 + c1 * uu1 + c2 * uu2 + c3 * uu3);
        }
        __syncthreads();
        if (t < 192) {
            int w = t >> 6, e = t & 63;
            double acc = 0.0;
#pragma unroll
            for (int j = 0; j < 64; ++j)
                acc += comb[w][j] * (double)w2[j * 64 + e];
            v[w][e] = acc;
        }
        __syncthreads();
        for (int rep = 0; rep < 3; ++rep) {
            int d = t & 127, g = t >> 7;
            const float* W = g ? wga : wgr;
            const float* B = g ? bga : bgr;
            double acc = (double)B[d];
#pragma unroll
            for (int j = 0; j < 64; ++j)
                acc += v[rep][j] * (double)W[j * GDIM + d];
            hgg[rep][g][d] = acc;
        }
        __syncthreads();
        if (t < 128) {
            if (k >= 2) Phi[t] += hgg[0][0][t] * sigm_d(hgg[0][1][t]);
            double hg = Phi[t] + hgg[2][0][t] * sigm_d(hgg[2][1][t]);
            if (k >= 1) hg += hgg[1][0][t] * sigm_d(hgg[1][1][t]);
            hgraph[t] = hg;
        } else if (t < 192) {
            hlastS[t - 128] = v[2][t - 128];
        }
        __syncthreads();
    }
}

__global__ __launch_bounds__(256) void k_rank_set(const int* __restrict__ idxs_sel, int* __restrict__ rank,
                           float* __restrict__ out) {
    int t = blockIdx.x * 256 + threadIdx.x;
    if (t < NSEQ) {
        atomicMin(&rank[idxs_sel[t]], t);
        out[(size_t)NSEQ * NPOOL + t] = (float)idxs_sel[t];
    }
}

__global__ __launch_bounds__(256) void k_fill(const double* __restrict__ s, const double* __restrict__ c,
                       const int* __restrict__ rank, const float* __restrict__ be, float* __restrict__ out) {
    size_t t = (size_t)blockIdx.x * 256 + threadIdx.x;   // NSEQ*NPOOL
    int k = (int)(t >> 12);
    int i = (int)(t & 4095);
    double bed = (double)be[0];
    bool masked = rank[i] < k;
    out[t] = masked ? (float)bed : (float)(s[i] + c[k] + bed);
}

extern "C" void kernel_launch(void* const* d_in, const int* in_sizes, int n_in,
                              void* d_out, int out_size, void* d_ws, size_t ws_size,
                              hipStream_t stream) {
    const float* x    = (const float*)d_in[0];
    const float* f    = (const float*)d_in[1];
    const float* amat = (const float*)d_in[2];
    const float* dmat = (const float*)d_in[3];
    const float* wf   = (const float*)d_in[4];
    const float* bf   = (const float*)d_in[5];
    const float* w1   = (const float*)d_in[6];
    const float* w2   = (const float*)d_in[7];
    const float* wgr  = (const float*)d_in[8];
    const float* bgr  = (const float*)d_in[9];
    const float* wga  = (const float*)d_in[10];
    const float* bga  = (const float*)d_in[11];
    const float* we   = (const float*)d_in[12];
    const float* be   = (const float*)d_in[13];
    const float* wsq  = (const float*)d_in[14];
    const float* bsq  = (const float*)d_in[15];
    float* out = (float*)d_out;

    char* p = (char*)d_ws;
    const size_t BIG = (size_t)NPOOL * 64 * sizeof(double);   // 2 MB
    double* R    = (double*)p; p += BIG;
    double* Fin  = (double*)p; p += BIG;
    double* T1   = (double*)p; p += BIG;
    double* T2   = (double*)p; p += BIG;
    double* T3   = (double*)p; p += BIG;
    double* seqe = (double*)p; p += (size_t)NSEQ * SDIM * sizeof(double);
    double* s    = (double*)p; p += (size_t)NPOOL * sizeof(double);
    double* skey = (double*)p; p += (size_t)NSEQ * sizeof(double);
    double* phi_inf  = (double*)p; p += 2 * (size_t)NSEQ * GDIM * sizeof(double);
    double* phi_pair = (double*)p; p += 2 * (size_t)NSEQ * GDIM * sizeof(double);
    double* hgr   = (double*)p; p += 2 * (size_t)NSEQ * GDIM * sizeof(double);
    double* hlast = (double*)p; p += 2 * (size_t)NSEQ * 64 * sizeof(double);
    double* cA    = (double*)p; p += (size_t)NSEQ * sizeof(double);
    double* cB    = (double*)p; p += (size_t)NSEQ * sizeof(double);
    double* c     = (double*)p; p += (size_t)NSEQ * sizeof(double);
    int* order    = (int*)p; p += 2048;
    int* orderB   = (int*)p; p += 2048;
    int* idxs_sel = (int*)p; p += 2048;
    int* rank     = (int*)p; p += (size_t)NPOOL * sizeof(int);
    int* flagA    = (int*)p; p += 256;
    int* flagB    = (int*)p; p += 256;
    int* mode     = (int*)p; p += 256;

    dim3 ggrid(NPOOL / 64, SPLITK);   // 64 x 16 = 1024 blocks

    k_prep<<<1024, 256, 0, stream>>>(f, wf, bf, Fin, R, T1, T2, T3);  // also zeroes T1,T2,T3
    k_seqe<<<32, 256, 0, stream>>>(x, wsq, bsq, seqe, rank);          // also inits rank

    gemm_f64_v10<<<ggrid, 256, 0, stream>>>(dmat, R, T1);    // t1 = d @ R
    gemm_f64_v10<<<ggrid, 256, 0, stream>>>(amat, T1, T2);   // t2 = a @ t1
    gemm_f64_v10<<<ggrid, 256, 0, stream>>>(dmat, T2, T3);   // t3 = d @ t2

    k_head<<<NPOOL / 4, 256, 0, stream>>>(T3, w1, we, s);
    k_sort3<<<1, 1024, 0, stream>>>(s, order, skey, orderB);

    // both hypotheses fused (A: sorted order; B: repeat order[0])
    k_perk2<<<2 * NSEQ, 256, 0, stream>>>(Fin, order, orderB, w2, wgr, bgr, wga, bga, phi_inf, phi_pair, hlast);
    k_scan2<<<2 * GDIM, 512, 0, stream>>>(phi_inf, phi_pair, hgr);
    k_c2<<<2 * NSEQ, 64, 0, stream>>>(hlast, hgr, seqe, we, cA, cB);
    k_verify2<<<2, 512, 0, stream>>>(skey, cA, cB, flagA, flagB);

    k_select<<<1, 512, 0, stream>>>(flagA, flagB, cA, cB, order, c, idxs_sel, mode);
    k_fallback<<<1, 256, 0, stream>>>(mode, Fin, order, skey, seqe, w2, wgr, bgr, wga, bga, we, idxs_sel, c);

    k_rank_set<<<2, 256, 0, stream>>>(idxs_sel, rank, out);
    k_fill<<<(NSEQ * NPOOL) / 256, 256, 0, stream>>>(s, c, rank, be, out);
}

// Round 11
// 460.712 us; speedup vs baseline: 4.5971x; 1.0090x over previous
//
#include <hip/hip_runtime.h>
#include <math.h>

#define NPOOL 4096
#define NSEQ  512
#define NF    20
#define EDIM  64
#define GDIM  128
#define SDIM  16
#define ALPH  20
#define SPLITK 16
#define KSLICE (NPOOL / SPLITK)   // 256
#define KSTEPS (KSLICE / 32)      // 8

__device__ __forceinline__ double relu_d(double x){ return x > 0.0 ? x : 0.0; }
__device__ __forceinline__ double sigm_d(double x){ return 1.0 / (1.0 + exp(-x)); }

__device__ __forceinline__ unsigned long long sortable_u64(double x) {
    x = x + 0.0;                                  // canonicalize -0 -> +0
    unsigned long long b = (unsigned long long)__double_as_longlong(x);
    return b ^ ((b >> 63) ? ~0ULL : 0x8000000000000000ULL);
}

// Fin[i][e] = f @ w_feat + b_feat (f64); R = relu(Fin). Also zeroes T1,T2,T3,
// computes seq_embed (low 8192 threads) and inits rank (low 4096 threads).
__global__ __launch_bounds__(256) void k_prep(const float* __restrict__ f, const float* __restrict__ wf,
                       const float* __restrict__ bf, double* __restrict__ Fin, double* __restrict__ R,
                       double* __restrict__ T1z, double* __restrict__ T2z, double* __restrict__ T3z,
                       const float* __restrict__ x, const float* __restrict__ wsq,
                       const float* __restrict__ bsq, double* __restrict__ seqe, int* __restrict__ rank) {
    int t = blockIdx.x * 256 + threadIdx.x;   // NPOOL*EDIM
    int i = t >> 6, e = t & 63;
    double acc = (double)bf[e];
#pragma unroll
    for (int j = 0; j < NF; ++j)
        acc += (double)f[i * NF + j] * (double)wf[j * EDIM + e];
    Fin[t] = acc;
    R[t] = acc > 0.0 ? acc : 0.0;
    T1z[t] = 0.0; T2z[t] = 0.0; T3z[t] = 0.0;
    if (t < NSEQ * SDIM) {                    // fused seq_embed
        int k = t >> 4, s = t & 15;
        double a2 = (double)bsq[s];
#pragma unroll
        for (int q = 0; q < ALPH; ++q)
            a2 += (double)x[k * ALPH + q] * (double)wsq[q * SDIM + s];
        seqe[t] = a2;
    }
    if (t < NPOOL) rank[t] = 1 << 30;         // fused rank init
}

// C(4096x64 f64) += A(4096x4096 f32) @ B(4096x64 f64), split-K, VALU f64 FMA.
// v10 structure (== v9 schedule, 80.6-82.0us measured, ~80% of LDS-issue floor).
__global__ __launch_bounds__(256, 4) void gemm_f64_v10(const float* __restrict__ A, const double* __restrict__ B,
                                                       double* __restrict__ C) {
    __shared__ float  As[32][68];   // [k][row-slot swizzled], f32 (8.7 KB)
    __shared__ double Bs[32][66];   // [k][col] (16.9 KB)
    int t  = threadIdx.x;
    int tx = t & 15;
    int ty = t >> 4;
    int row0 = blockIdx.x * 64;
    int k0   = blockIdx.y * KSLICE;
    int kq = t & 3, kb = kq << 3;    // staging: this thread covers k = kb..kb+7
    int ar = t >> 2;                 // staging A row (0..63)
    int rs = ar ^ (kq << 2);         // swizzled slot (v8/v9-verified)
    int e0 = 2 * t, e1 = e0 + 512, e2 = e0 + 1024, e3 = e0 + 1536;

    const float* Abase = A + (size_t)(row0 + ar) * NPOOL + kq * 8;

    double acc[4][4] = {};
    float4  a0, a1;
    double2 b0, b1, b2, b3;

#define LOADG(KT)                                                                 \
    {                                                                             \
        a0 = *(const float4*)(Abase + (KT));                                      \
        a1 = *(const float4*)(Abase + (KT) + 4);                                  \
        b0 = *(const double2*)&B[(size_t)((KT) + (e0 >> 6)) * 64 + (e0 & 63)];    \
        b1 = *(const double2*)&B[(size_t)((KT) + (e1 >> 6)) * 64 + (e1 & 63)];    \
        b2 = *(const double2*)&B[(size_t)((KT) + (e2 >> 6)) * 64 + (e2 & 63)];    \
        b3 = *(const double2*)&B[(size_t)((KT) + (e3 >> 6)) * 64 + (e3 & 63)];    \
    }

#define STORELDS()                                                                \
    {                                                                             \
        As[kb + 0][rs] = a0.x; As[kb + 1][rs] = a0.y;                             \
        As[kb + 2][rs] = a0.z; As[kb + 3][rs] = a0.w;                             \
        As[kb + 4][rs] = a1.x; As[kb + 5][rs] = a1.y;                             \
        As[kb + 6][rs] = a1.z; As[kb + 7][rs] = a1.w;                             \
        *(double2*)&Bs[e0 >> 6][e0 & 63] = b0;                                    \
        *(double2*)&Bs[e1 >> 6][e1 & 63] = b1;                                    \
        *(double2*)&Bs[e2 >> 6][e2 & 63] = b2;                                    \
        *(double2*)&Bs[e3 >> 6][e3 & 63] = b3;                                    \
    }

#define COMPUTE32()                                                               \
    {                                                                             \
        _Pragma("unroll")                                                         \
        for (int kk = 0; kk < 32; ++kk) {                                         \
            int abase = 4 * (ty ^ (kk >> 3));                                     \
            float4 af = *(const float4*)&As[kk][abase];                           \
            double a[4] = {(double)af.x, (double)af.y, (double)af.z, (double)af.w}; \
            double2 q01 = *(const double2*)&Bs[kk][2 * tx];                       \
            double2 q23 = *(const double2*)&Bs[kk][2 * tx + 32];                  \
            double b[4] = {q01.x, q01.y, q23.x, q23.y};                           \
            _Pragma("unroll")                                                     \
            for (int i = 0; i < 4; ++i)                                           \
                _Pragma("unroll")                                                 \
                for (int j = 0; j < 4; ++j)                                       \
                    acc[i][j] = fma(a[i], b[j], acc[i][j]);                       \
        }                                                                         \
    }

    LOADG(k0)
    STORELDS()
    __syncthreads();

    for (int step = 0; step < KSTEPS - 1; ++step) {
        int ktn = k0 + 32 * (step + 1);
        LOADG(ktn)
        COMPUTE32()
        __syncthreads();
        STORELDS()
        __syncthreads();
    }
    COMPUTE32()

#undef LOADG
#undef STORELDS
#undef COMPUTE32

    int cc[4] = {2 * tx, 2 * tx + 1, 2 * tx + 32, 2 * tx + 33};
#pragma unroll
    for (int i = 0; i < 4; ++i)
#pragma unroll
        for (int j = 0; j < 4; ++j)
            unsafeAtomicAdd(&C[(size_t)(row0 + 4 * ty + i) * 64 + cc[j]], acc[i][j]);
}

// s[i] = relu(T3[i,:] @ w_gcn1) . w_edge[0:64]
// 256 blocks x 4 row-groups: w1 staged ONCE per block (was 1024 stagings = 16MB L2 re-traffic).
__global__ __launch_bounds__(256) void k_head(const double* __restrict__ T3, const float* __restrict__ w1,
                       const float* __restrict__ we, double* __restrict__ s) {
    __shared__ float w1s[64 * 64];
    int tt = threadIdx.x;
    for (int i = tt; i < 64 * 64; i += 256) w1s[i] = w1[i];
    __syncthreads();
    int e = tt & 63;
    double wev = (double)we[e];
#pragma unroll
    for (int g = 0; g < 4; ++g) {
        int row = ((blockIdx.x * 256 + tt) >> 6) + g * 1024;
        const double* r = T3 + (size_t)row * 64;
        double h = 0.0;
#pragma unroll
        for (int c = 0; c < 64; ++c)
            h += r[c] * (double)w1s[c * 64 + e];
        double p = (h > 0.0 ? h : 0.0) * wev;
        for (int off = 32; off; off >>= 1) p += __shfl_down(p, off, 64);
        if (e == 0) s[row] = p;
    }
}

// Full sort of 4096 keys (desc, idx asc on ties) via packed-u64 register bitonic.
__global__ __launch_bounds__(1024) void k_sort3(const double* __restrict__ s, int* __restrict__ order,
                        double* __restrict__ skey, int* __restrict__ orderB) {
    __shared__ unsigned long long P[NPOOL];   // 32 KB
    __shared__ int idxF[NPOOL];               // 16 KB (fallback only)
    __shared__ int fbS;
    int t = threadIdx.x;
    if (t == 0) fbS = 0;
    unsigned long long v[4];
#pragma unroll
    for (int i = 0; i < 4; ++i) {
        int e = 4 * t + i;
        unsigned long long srt = sortable_u64(s[e]);
        v[i] = ((~(srt >> 12)) << 12) | (unsigned long long)e;
    }

#define SHFL_ROUND(jj, kk)                                                        \
    {                                                                             \
        int lm = (int)((jj) >> 2);                                                \
        _Pragma("unroll")                                                         \
        for (int i = 0; i < 4; ++i) {                                             \
            unsigned long long p = (unsigned long long)__shfl_xor((long long)v[i], lm, 64); \
            unsigned e = 4u * (unsigned)t + (unsigned)i;                          \
            bool takeMin = (((e & (jj)) == 0u) == ((e & (kk)) == 0u));            \
            unsigned long long mn = v[i] < p ? v[i] : p;                          \
            unsigned long long mx = v[i] < p ? p : v[i];                          \
            v[i] = takeMin ? mn : mx;                                             \
        }                                                                         \
    }

#define LOCAL_ROUNDS(kk)                                                          \
    {                                                                             \
        if ((kk) >= 4) {                                                          \
            _Pragma("unroll")                                                     \
            for (int i = 0; i < 2; ++i) {                                         \
                unsigned e = 4u * (unsigned)t + (unsigned)i;                      \
                bool asc = ((e & (kk)) == 0u);                                    \
                unsigned long long a = v[i], b = v[i + 2];                        \
                bool sw = asc ? (a > b) : (a < b);                                \
                v[i] = sw ? b : a; v[i + 2] = sw ? a : b;                         \
            }                                                                     \
        }                                                                         \
        _Pragma("unroll")                                                         \
        for (int i = 0; i < 4; i += 2) {                                          \
            unsigned e = 4u * (unsigned)t + (unsigned)i;                          \
            bool asc = ((e & (kk)) == 0u);                                        \
            unsigned long long a = v[i], b = v[i + 1];                            \
            bool sw = asc ? (a > b) : (a < b);                                    \
            v[i] = sw ? b : a; v[i + 1] = sw ? a : b;                             \
        }                                                                         \
    }

    // phase 1: k = 2..256 (purely intra-wave)
    for (unsigned k = 2; k <= 256; k <<= 1) {
        for (unsigned j = k >> 1; j >= 4; j >>= 1) SHFL_ROUND(j, k)
        LOCAL_ROUNDS(k)
    }
    // phase 2: k = 512..4096 (j>=256 via LDS, rest intra-wave)
    for (unsigned k = 512; k <= 4096; k <<= 1) {
        for (unsigned j = k >> 1; j >= 256; j >>= 1) {
            __syncthreads();
            P[4 * t + 0] = v[0]; P[4 * t + 1] = v[1];
            P[4 * t + 2] = v[2]; P[4 * t + 3] = v[3];
            __syncthreads();
            unsigned base = (4u * (unsigned)t) ^ j;
#pragma unroll
            for (int i = 0; i < 4; ++i) {
                unsigned e = 4u * (unsigned)t + (unsigned)i;
                unsigned long long p = P[base + i];
                bool takeMin = (((e & j) == 0u) == ((e & k) == 0u));
                unsigned long long mn = v[i] < p ? v[i] : p;
                unsigned long long mx = v[i] < p ? p : v[i];
                v[i] = takeMin ? mn : mx;
            }
        }
        for (unsigned j = 128; j >= 4; j >>= 1) SHFL_ROUND(j, k)
        LOCAL_ROUNDS(k)
    }
#undef SHFL_ROUND
#undef LOCAL_ROUNDS

    __syncthreads();
    P[4 * t + 0] = v[0]; P[4 * t + 1] = v[1];
    P[4 * t + 2] = v[2]; P[4 * t + 3] = v[3];
    __syncthreads();
    // truncation-tie guard over positions 0..512 (adjacent pairs)
    if (t < 512) {
        unsigned long long pa = P[t], pb = P[t + 1];
        if ((pa >> 12) == (pb >> 12)) {
            int ia = (int)(pa & 4095ULL), ib = (int)(pb & 4095ULL);
            if (sortable_u64(s[ia]) != sortable_u64(s[ib])) atomicOr(&fbS, 1);
        }
    }
    __syncthreads();
    if (fbS == 0) {
        if (t < NSEQ) {
            int id = (int)(P[t] & 4095ULL);
            order[t] = id; skey[t] = s[id]; orderB[t] = (int)(P[0] & 4095ULL);
        }
        return;
    }
    // exact fallback: full bitonic on (sortable64, idx)
    for (int i = t; i < NPOOL; i += 1024) { P[i] = sortable_u64(s[i]); idxF[i] = i; }
    __syncthreads();
    for (int k2 = 2; k2 <= NPOOL; k2 <<= 1) {
        for (int j = k2 >> 1; j > 0; j >>= 1) {
            for (int tt = t; tt < NPOOL; tt += 1024) {
                int l = tt ^ j;
                if (l > tt) {
                    unsigned long long ka = P[tt], kb = P[l];
                    int ia = idxF[tt], ib = idxF[l];
                    bool aBefore = (ka > kb) || (ka == kb && ia < ib);
                    bool asc = ((tt & k2) == 0);
                    if (asc ? !aBefore : aBefore) { P[tt] = kb; P[l] = ka; idxF[tt] = ib; idxF[l] = ia; }
                }
            }
            __syncthreads();
        }
    }
    for (int tt = t; tt < NSEQ; tt += 1024) {
        int id = idxF[tt];
        order[tt] = id; skey[tt] = s[id]; orderB[tt] = idxF[0];
    }
}

// per-k recurrence pieces for BOTH hypotheses (which = blockIdx.x>>9): A uses orderA, B uses orderB
__global__ __launch_bounds__(256) void k_perk2(const double* __restrict__ Fin, const int* __restrict__ orderA,
                       const int* __restrict__ orderBv,
                       const float* __restrict__ w2, const float* __restrict__ wgr, const float* __restrict__ bgr,
                       const float* __restrict__ wga, const float* __restrict__ bga,
                       double* __restrict__ phi_inf, double* __restrict__ phi_pair, double* __restrict__ hlast) {
    const double r2 = 0.70710678118654752440;
    const double r3 = 0.57735026918962576451;
    __shared__ double u[4][64];
    __shared__ double comb[3][64];
    __shared__ double v[3][64];
    __shared__ double hgg[3][2][GDIM];
    int which = blockIdx.x >> 9;
    int k = blockIdx.x & (NSEQ - 1);
    const int* order = which ? orderBv : orderA;
    double* pi = phi_inf  + (size_t)which * NSEQ * GDIM;
    double* pp = phi_pair + (size_t)which * NSEQ * GDIM;
    double* hl = hlast    + (size_t)which * NSEQ * 64;
    int t = threadIdx.x;
    {
        int w = t >> 6, e = t & 63;
        int j = k - 3 + w;
        u[w][e] = (j >= 0) ? Fin[(size_t)order[j] * 64 + e] : 0.0;
    }
    __syncthreads();
    if (t < 192) {
        int w = t >> 6, e = t & 63;
        double dh_km3 = (k - 3 == 0) ? r2 : r3;
        double dh_km2 = (k - 2 == 0) ? r2 : r3;
        double dh_km1 = (k - 1 == 0) ? r2 : r3;
        double outer, c0, c1, c2, c3;
        if (w == 0) {        // v_{k-2} (final form)
            outer = dh_km2; c0 = dh_km3; c1 = dh_km2; c2 = dh_km1; c3 = 0.0;
        } else if (w == 1) { // v_{k-1}^{(k)}
            outer = dh_km1; c0 = 0.0; c1 = dh_km2; c2 = dh_km1; c3 = r2;
        } else {             // v_k^{(k)}
            if (k == 0) { outer = 1.0; c0 = c1 = c2 = 0.0; c3 = 1.0; }
            else        { outer = r2;  c0 = c1 = 0.0; c2 = dh_km1; c3 = r2; }
        }
        comb[w][e] = outer * (c0 * u[0][e] + c1 * u[1][e] + c2 * u[2][e] + c3 * u[3][e]);
    }
    __syncthreads();
    if (t < 192) {
        int w = t >> 6, e = t & 63;
        double acc = 0.0;
#pragma unroll
        for (int j = 0; j < 64; ++j)
            acc += comb[w][j] * (double)w2[j * 64 + e];
        v[w][e] = acc;
    }
    __syncthreads();
    for (int rep = 0; rep < 3; ++rep) {
        int d = t & 127, g = t >> 7;
        const float* W = g ? wga : wgr;
        const float* B = g ? bga : bgr;
        double acc = (double)B[d];
#pragma unroll
        for (int j = 0; j < 64; ++j)
            acc += v[rep][j] * (double)W[j * GDIM + d];
        hgg[rep][g][d] = acc;
    }
    __syncthreads();
    if (t < 128) {
        if (k >= 2) pi[(size_t)(k - 2) * GDIM + t] = hgg[0][0][t] * sigm_d(hgg[0][1][t]);
        double ppv = hgg[2][0][t] * sigm_d(hgg[2][1][t]);
        if (k >= 1) ppv += hgg[1][0][t] * sigm_d(hgg[1][1][t]);
        pp[(size_t)k * GDIM + t] = ppv;
    } else if (t < 192) {
        hl[(size_t)k * 64 + (t - 128)] = v[2][t - 128];
    }
}

// per-dim prefix scan for both hypotheses: hgr[k] = sum_{j<=k-2} phi_inf[j] + phi_pair[k]
__global__ __launch_bounds__(512) void k_scan2(const double* __restrict__ phi_inf, const double* __restrict__ phi_pair,
                       double* __restrict__ hgr) {
    __shared__ double sb[NSEQ];
    int which = blockIdx.x >> 7;
    int d = blockIdx.x & (GDIM - 1), t = threadIdx.x;
    const double* pi = phi_inf  + (size_t)which * NSEQ * GDIM;
    const double* pp = phi_pair + (size_t)which * NSEQ * GDIM;
    double* hg = hgr + (size_t)which * NSEQ * GDIM;
    sb[t] = (t >= 2) ? pi[(size_t)(t - 2) * GDIM + d] : 0.0;
    for (int off = 1; off < NSEQ; off <<= 1) {
        __syncthreads();
        double add = (t >= off) ? sb[t - off] : 0.0;
        __syncthreads();
        sb[t] += add;
    }
    __syncthreads();
    hg[(size_t)t * GDIM + d] = sb[t] + pp[(size_t)t * GDIM + d];
}

// c_k for both hypotheses; one wave per (which, k)
__global__ __launch_bounds__(64) void k_c2(const double* __restrict__ hlast, const double* __restrict__ hgr,
                   const double* __restrict__ seqe, const float* __restrict__ we,
                   double* __restrict__ cA, double* __restrict__ cB) {
    int which = blockIdx.x >> 9;
    int k = blockIdx.x & (NSEQ - 1), j = threadIdx.x;
    const double* hl = hlast + (size_t)which * NSEQ * 64;
    const double* hg = hgr   + (size_t)which * NSEQ * GDIM;
    double* c = which ? cB : cA;
    double ts = 0.0;
    if (k > 0) {
        ts += relu_d(hl[(size_t)(k - 1) * 64 + j]) * (double)we[64 + j];
        ts += relu_d(hg[(size_t)(k - 1) * GDIM + j]) * (double)we[144 + j];
        ts += relu_d(hg[(size_t)(k - 1) * GDIM + 64 + j]) * (double)we[208 + j];
    }
    if (j < 16) ts += relu_d(seqe[(size_t)k * SDIM + j]) * (double)we[128 + j];
    for (int off = 32; off; off >>= 1) ts += __shfl_down(ts, off, 64);
    if (j == 0) c[k] = ts;
}

// fused verify(A,B) + select + rank/out write (fast paths only; mode 2 -> fallback handles)
__global__ __launch_bounds__(1024) void k_finalize(const double* __restrict__ skey,
                        const double* __restrict__ cA, const double* __restrict__ cB,
                        const int* __restrict__ order, double* __restrict__ c,
                        int* __restrict__ idxs_sel, int* __restrict__ mode,
                        int* __restrict__ rank, float* __restrict__ out) {
    __shared__ int badA, badB;
    int t = threadIdx.x;
    if (t == 0) { badA = 0; badB = 0; }
    __syncthreads();
    if (t >= 1 && t < NSEQ) {
        if (!(skey[t] + cA[t] > 0.0)) atomicOr(&badA, 1);
        if (skey[1] + cB[t] > 0.0)    atomicOr(&badB, 1);
    }
    __syncthreads();
    int m = (badA == 0) ? 0 : ((badB == 0) ? 1 : 2);
    if (t == 0) mode[0] = m;
    if (m == 2) return;
    if (t < NSEQ) {
        double cv = (m == 0) ? cA[t] : cB[t];
        int idx = (m == 0) ? order[t] : order[0];
        c[t] = cv;
        idxs_sel[t] = idx;
        atomicMin(&rank[idx], t);
        out[(size_t)NSEQ * NPOOL + t] = (float)idx;
    }
}

// exact sequential fallback (runs only when both fast paths invalid); now also writes rank/out
__global__ __launch_bounds__(256) void k_fallback(const int* __restrict__ mode,
        const double* __restrict__ Fin, const int* __restrict__ order, const double* __restrict__ skey,
        const double* __restrict__ seqe,
        const float* __restrict__ w2, const float* __restrict__ wgr, const float* __restrict__ bgr,
        const float* __restrict__ wga, const float* __restrict__ bga, const float* __restrict__ we,
        int* __restrict__ idxs_sel, double* __restrict__ c, int* __restrict__ rank, float* __restrict__ out) {
    if (mode[0] != 2) return;
    const double r2 = 0.70710678118654752440;
    const double r3 = 0.57735026918962576451;
    __shared__ double u[4][64];
    __shared__ double comb[3][64];
    __shared__ double v[3][64];
    __shared__ double hgg[3][2][GDIM];
    __shared__ double Phi[GDIM], hgraph[GDIM], hlastS[64];
    __shared__ int selS, ptrS, minS_;
    int t = threadIdx.x;
    if (t < 64) { u[0][t] = u[1][t] = u[2][t] = u[3][t] = 0.0; hlastS[t] = 0.0; }
    if (t < 128) { Phi[t] = 0.0; hgraph[t] = 0.0; }
    if (t == 0) { ptrS = 0; minS_ = 0x7fffffff; }
    __syncthreads();
    for (int k = 0; k < NSEQ; ++k) {
        if (t < 64) {
            int j = t;
            double ts = relu_d(hlastS[j]) * (double)we[64 + j]
                      + relu_d(hgraph[j]) * (double)we[144 + j]
                      + relu_d(hgraph[64 + j]) * (double)we[208 + j];
            if (j < 16) ts += relu_d(seqe[(size_t)k * SDIM + j]) * (double)we[128 + j];
            for (int off = 32; off; off >>= 1) ts += __shfl_down(ts, off, 64);
            if (j == 0) {
                c[k] = ts;
                int ptr = ptrS, idx;
                if (ptr == 0) { idx = order[0]; minS_ = idx; ptrS = 1; }
                else if (skey[ptr] + ts > 0.0) {
                    idx = order[ptr];
                    if (idx < minS_) minS_ = idx;
                    ptrS = ptr + 1;
                } else idx = minS_;
                selS = idx;
                idxs_sel[k] = idx;
            }
        }
        __syncthreads();
        int idx = selS;
        if (t < 64) u[k & 3][t] = Fin[(size_t)idx * 64 + t];
        __syncthreads();
        if (t < 192) {
            int w = t >> 6, e = t & 63;
            double dh_km3 = (k - 3 == 0) ? r2 : r3;
            double dh_km2 = (k - 2 == 0) ? r2 : r3;
            double dh_km1 = (k - 1 == 0) ? r2 : r3;
            double outer, c0, c1, c2, c3;
            if (w == 0) {
                outer = dh_km2; c0 = dh_km3; c1 = dh_km2; c2 = dh_km1; c3 = 0.0;
            } else if (w == 1) {
                outer = dh_km1; c0 = 0.0; c1 = dh_km2; c2 = dh_km1; c3 = r2;
            } else {
                if (k == 0) { outer = 1.0; c0 = c1 = c2 = 0.0; c3 = 1.0; }
                else        { outer = r2;  c0 = c1 = 0.0; c2 = dh_km1; c3 = r2; }
            }
            double uu0 = u[(k - 3) & 3][e], uu1 = u[(k - 2) & 3][e], uu2 = u[(k - 1) & 3][e], uu3 = u[k & 3][e];
            comb[w][e] = outer * (c0 * uu0 + c1 * uu1 + c2 * uu2 + c3 * uu3);
        }
        __syncthreads();
        if (t < 192) {
            int w = t >> 6, e = t & 63;
            double acc = 0.0;
#pragma unroll
            for (int j = 0; j < 64; ++j)
                acc += comb[w][j] * (double)w2[j * 64 + e];
            v[w][e] = acc;
        }
        __syncthreads();
        for (int rep = 0; rep < 3; ++rep) {
            int d = t & 127, g = t >> 7;
            const float* W = g ? wga : wgr;
            const float* B = g ? bga : bgr;
            double acc = (double)B[d];
#pragma unroll
            for (int j = 0; j < 64; ++j)
                acc += v[rep][j] * (double)W[j * GDIM + d];
            hgg[rep][g][d] = acc;
        }
        __syncthreads();
        if (t < 128) {
            if (k >= 2) Phi[t] += hgg[0][0][t] * sigm_d(hgg[0][1][t]);
            double hg = Phi[t] + hgg[2][0][t] * sigm_d(hgg[2][1][t]);
            if (k >= 1) hg += hgg[1][0][t] * sigm_d(hgg[1][1][t]);
            hgraph[t] = hg;
        } else if (t < 192) {
            hlastS[t - 128] = v[2][t - 128];
        }
        __syncthreads();
    }
    // rank/out epilogue (k_finalize skipped these in mode 2)
    for (int k2 = t; k2 < NSEQ; k2 += 256) {
        int idx = idxs_sel[k2];
        atomicMin(&rank[idx], k2);
        out[(size_t)NSEQ * NPOOL + k2] = (float)idx;
    }
}

__global__ __launch_bounds__(256) void k_fill(const double* __restrict__ s, const double* __restrict__ c,
                       const int* __restrict__ rank, const float* __restrict__ be, float* __restrict__ out) {
    size_t t = (size_t)blockIdx.x * 256 + threadIdx.x;   // NSEQ*NPOOL
    int k = (int)(t >> 12);
    int i = (int)(t & 4095);
    double bed = (double)be[0];
    bool masked = rank[i] < k;
    out[t] = masked ? (float)bed : (float)(s[i] + c[k] + bed);
}

extern "C" void kernel_launch(void* const* d_in, const int* in_sizes, int n_in,
                              void* d_out, int out_size, void* d_ws, size_t ws_size,
                              hipStream_t stream) {
    const float* x    = (const float*)d_in[0];
    const float* f    = (const float*)d_in[1];
    const float* amat = (const float*)d_in[2];
    const float* dmat = (const float*)d_in[3];
    const float* wf   = (const float*)d_in[4];
    const float* bf   = (const float*)d_in[5];
    const float* w1   = (const float*)d_in[6];
    const float* w2   = (const float*)d_in[7];
    const float* wgr  = (const float*)d_in[8];
    const float* bgr  = (const float*)d_in[9];
    const float* wga  = (const float*)d_in[10];
    const float* bga  = (const float*)d_in[11];
    const float* we   = (const float*)d_in[12];
    const float* be   = (const float*)d_in[13];
    const float* wsq  = (const float*)d_in[14];
    const float* bsq  = (const float*)d_in[15];
    float* out = (float*)d_out;

    char* p = (char*)d_ws;
    const size_t BIG = (size_t)NPOOL * 64 * sizeof(double);   // 2 MB
    double* R    = (double*)p; p += BIG;
    double* Fin  = (double*)p; p += BIG;
    double* T1   = (double*)p; p += BIG;
    double* T2   = (double*)p; p += BIG;
    double* T3   = (double*)p; p += BIG;
    double* seqe = (double*)p; p += (size_t)NSEQ * SDIM * sizeof(double);
    double* s    = (double*)p; p += (size_t)NPOOL * sizeof(double);
    double* skey = (double*)p; p += (size_t)NSEQ * sizeof(double);
    double* phi_inf  = (double*)p; p += 2 * (size_t)NSEQ * GDIM * sizeof(double);
    double* phi_pair = (double*)p; p += 2 * (size_t)NSEQ * GDIM * sizeof(double);
    double* hgr   = (double*)p; p += 2 * (size_t)NSEQ * GDIM * sizeof(double);
    double* hlast = (double*)p; p += 2 * (size_t)NSEQ * 64 * sizeof(double);
    double* cA    = (double*)p; p += (size_t)NSEQ * sizeof(double);
    double* cB    = (double*)p; p += (size_t)NSEQ * sizeof(double);
    double* c     = (double*)p; p += (size_t)NSEQ * sizeof(double);
    int* order    = (int*)p; p += 2048;
    int* orderB   = (int*)p; p += 2048;
    int* idxs_sel = (int*)p; p += 2048;
    int* rank     = (int*)p; p += (size_t)NPOOL * sizeof(int);
    int* flagA    = (int*)p; p += 256;
    int* flagB    = (int*)p; p += 256;
    int* mode     = (int*)p; p += 256;
    (void)flagA; (void)flagB;

    dim3 ggrid(NPOOL / 64, SPLITK);   // 64 x 16 = 1024 blocks

    k_prep<<<1024, 256, 0, stream>>>(f, wf, bf, Fin, R, T1, T2, T3, x, wsq, bsq, seqe, rank);

    gemm_f64_v10<<<ggrid, 256, 0, stream>>>(dmat, R, T1);    // t1 = d @ R
    gemm_f64_v10<<<ggrid, 256, 0, stream>>>(amat, T1, T2);   // t2 = a @ t1
    gemm_f64_v10<<<ggrid, 256, 0, stream>>>(dmat, T2, T3);   // t3 = d @ t2

    k_head<<<256, 256, 0, stream>>>(T3, w1, we, s);
    k_sort3<<<1, 1024, 0, stream>>>(s, order, skey, orderB);

    // both hypotheses fused (A: sorted order; B: repeat order[0])
    k_perk2<<<2 * NSEQ, 256, 0, stream>>>(Fin, order, orderB, w2, wgr, bgr, wga, bga, phi_inf, phi_pair, hlast);
    k_scan2<<<2 * GDIM, 512, 0, stream>>>(phi_inf, phi_pair, hgr);
    k_c2<<<2 * NSEQ, 64, 0, stream>>>(hlast, hgr, seqe, we, cA, cB);

    k_finalize<<<1, 1024, 0, stream>>>(skey, cA, cB, order, c, idxs_sel, mode, rank, out);
    k_fallback<<<1, 256, 0, stream>>>(mode, Fin, order, skey, seqe, w2, wgr, bgr, wga, bga, we, idxs_sel, c, rank, out);

    k_fill<<<(NSEQ * NPOOL) / 256, 256, 0, stream>>>(s, c, rank, be, out);
}